// Round 1
// baseline (6456.598 us; speedup 1.0000x reference)
//
#include <hip/hip_runtime.h>
#include <hip/hip_bf16.h>

#define EMB 256
#define NHEAD 4
#define HSZ 64
#define NLAYER 3
#define TBLK 2048
#define VOCAB 32000
#define BATCH 4
#define LNEPS 1e-5f
#define BT (BATCH * TBLK)   // 8192 rows

// ---------------------------------------------------------------------------
// Embedding: x[row, :] = tok_emb[idx[row], :] + pos_emb[row % T, :]
// ---------------------------------------------------------------------------
__global__ __launch_bounds__(64) void embed_kernel(
    const int* __restrict__ idx, const float* __restrict__ tok,
    const float* __restrict__ pos, float* __restrict__ x)
{
    const int row = blockIdx.x;
    const int t = row & (TBLK - 1);
    const int token = idx[row];
    const int e = threadIdx.x * 4;
    const float4 tv = *(const float4*)&tok[(size_t)token * EMB + e];
    const float4 pv = *(const float4*)&pos[(size_t)t * EMB + e];
    float4 o;
    o.x = tv.x + pv.x; o.y = tv.y + pv.y; o.z = tv.z + pv.z; o.w = tv.w + pv.w;
    *(float4*)&x[(size_t)row * EMB + e] = o;
}

// ---------------------------------------------------------------------------
// LayerNorm over E=256. One wave per row; population variance (jnp.var).
// ---------------------------------------------------------------------------
__global__ __launch_bounds__(64) void ln_kernel(
    const float* __restrict__ x, const float* __restrict__ g,
    const float* __restrict__ b, float* __restrict__ out)
{
    const int row = blockIdx.x;
    const int e = threadIdx.x * 4;
    const float4 xv = *(const float4*)&x[(size_t)row * EMB + e];
    float s1 = xv.x + xv.y + xv.z + xv.w;
    float s2 = xv.x * xv.x + xv.y * xv.y + xv.z * xv.z + xv.w * xv.w;
    #pragma unroll
    for (int off = 32; off >= 1; off >>= 1) {
        s1 += __shfl_xor(s1, off);
        s2 += __shfl_xor(s2, off);
    }
    const float mu  = s1 * (1.0f / EMB);
    const float var = s2 * (1.0f / EMB) - mu * mu;
    const float rs  = rsqrtf(var + LNEPS);
    const float4 gv = *(const float4*)&g[e];
    const float4 bv = *(const float4*)&b[e];
    float4 o;
    o.x = (xv.x - mu) * rs * gv.x + bv.x;
    o.y = (xv.y - mu) * rs * gv.y + bv.y;
    o.z = (xv.z - mu) * rs * gv.z + bv.z;
    o.w = (xv.w - mu) * rs * gv.w + bv.w;
    *(float4*)&out[(size_t)row * EMB + e] = o;
}

// ---------------------------------------------------------------------------
// Tiled fp32 GEMM: C[M,N] = A[M,K] @ B[K,N] (+bias) (+relu) (+residual)
// 64x64 tile, BK=16, 256 threads, 4x4 micro-tile per thread.
// RES never co-occurs with RELU in this model. res may alias C (in-place).
// ---------------------------------------------------------------------------
template<int BIAS, int RES, int RELU>
__global__ __launch_bounds__(256) void gemm_kernel(
    const float* __restrict__ A, const float* __restrict__ Bm,
    const float* __restrict__ bias, const float* res,
    float* C, int M, int N, int K)
{
    __shared__ float As[16][68];   // [k][m], padded
    __shared__ float Bs[16][68];   // [k][n], padded

    const int tid = threadIdx.x;
    const int bn = blockIdx.x, bm = blockIdx.y;
    const int tr = tid >> 4;          // 0..15
    const int tc = tid & 15;          // 0..15

    // staging indices
    const int ar = tid >> 2;          // 0..63 (A tile row)
    const int ac = (tid & 3) * 4;     // 0..12 (A tile col, float4)
    const int br = tid >> 4;          // 0..15 (B tile row)
    const int bc = (tid & 15) * 4;    // 0..60 (B tile col, float4)

    const float* Aptr = A + (size_t)(bm * 64 + ar) * K + ac;
    const float* Bptr = Bm + (size_t)br * N + bn * 64 + bc;

    float acc[4][4] = {};

    for (int k0 = 0; k0 < K; k0 += 16) {
        const float4 a4 = *(const float4*)(Aptr + k0);
        const float4 b4 = *(const float4*)(Bptr + (size_t)k0 * N);
        As[ac + 0][ar] = a4.x;
        As[ac + 1][ar] = a4.y;
        As[ac + 2][ar] = a4.z;
        As[ac + 3][ar] = a4.w;
        *(float4*)&Bs[br][bc] = b4;
        __syncthreads();
        #pragma unroll
        for (int kk = 0; kk < 16; ++kk) {
            const float4 a = *(const float4*)&As[kk][tr * 4];
            const float4 bq = *(const float4*)&Bs[kk][tc * 4];
            float av[4] = {a.x, a.y, a.z, a.w};
            float bv[4] = {bq.x, bq.y, bq.z, bq.w};
            #pragma unroll
            for (int i = 0; i < 4; ++i)
                #pragma unroll
                for (int j = 0; j < 4; ++j)
                    acc[i][j] = fmaf(av[i], bv[j], acc[i][j]);
        }
        __syncthreads();
    }

    const int rowbase = bm * 64 + tr * 4;
    const int colbase = bn * 64 + tc * 4;
    float4 bb = {0.f, 0.f, 0.f, 0.f};
    if (BIAS) bb = *(const float4*)&bias[colbase];
    #pragma unroll
    for (int i = 0; i < 4; ++i) {
        float4 o;
        o.x = acc[i][0]; o.y = acc[i][1]; o.z = acc[i][2]; o.w = acc[i][3];
        if (BIAS) { o.x += bb.x; o.y += bb.y; o.z += bb.z; o.w += bb.w; }
        if (RELU) {
            o.x = fmaxf(o.x, 0.f); o.y = fmaxf(o.y, 0.f);
            o.z = fmaxf(o.z, 0.f); o.w = fmaxf(o.w, 0.f);
        }
        const size_t off = (size_t)(rowbase + i) * N + colbase;
        if (RES) {
            const float4 rv = *(const float4*)&res[off];
            o.x += rv.x; o.y += rv.y; o.z += rv.z; o.w += rv.w;
        }
        *(float4*)&C[off] = o;
    }
}

// ---------------------------------------------------------------------------
// Causal flash attention, fp32. One wave per (b,h, 64-query tile); each
// thread owns one query row (q and o accumulator in registers), K/V tiles
// staged in LDS (broadcast reads). scale = 1/sqrt(E) = 1/16 (ref quirk).
// ---------------------------------------------------------------------------
__global__ __launch_bounds__(64) void attn_kernel(
    const float* __restrict__ q, const float* __restrict__ k,
    const float* __restrict__ v, float* __restrict__ y)
{
    __shared__ float Kl[64][68];
    __shared__ float Vl[64][68];

    const int tid = threadIdx.x;
    const int qt = blockIdx.x;          // query tile
    const int bh = blockIdx.y;          // b*H + h
    const int b = bh >> 2, h = bh & 3;
    const int qrow = qt * 64 + tid;
    const size_t base = ((size_t)b * TBLK) * EMB + h * HSZ;

    float qr[64];
    {
        const float* qp = q + base + (size_t)qrow * EMB;
        #pragma unroll
        for (int i = 0; i < 16; ++i) {
            const float4 t4 = *(const float4*)(qp + 4 * i);
            qr[4*i+0] = t4.x; qr[4*i+1] = t4.y; qr[4*i+2] = t4.z; qr[4*i+3] = t4.w;
        }
    }

    float m = -1e30f, l = 0.f;
    float o[64];
    #pragma unroll
    for (int d = 0; d < 64; ++d) o[d] = 0.f;
    const float scale = 0.0625f;   // 1/sqrt(256)

    for (int s0 = 0; s0 <= qt * 64; s0 += 64) {
        // stage K and V tiles (row tid)
        {
            const float* kp = k + base + (size_t)(s0 + tid) * EMB;
            const float* vp = v + base + (size_t)(s0 + tid) * EMB;
            #pragma unroll
            for (int i = 0; i < 16; ++i) {
                *(float4*)&Kl[tid][4*i] = *(const float4*)(kp + 4*i);
                *(float4*)&Vl[tid][4*i] = *(const float4*)(vp + 4*i);
            }
        }
        __syncthreads();

        int jmax = qrow - s0;
        if (jmax > 63) jmax = 63;
        for (int j = 0; j <= jmax; ++j) {
            float p0 = 0.f, p1 = 0.f, p2 = 0.f, p3 = 0.f;
            #pragma unroll
            for (int dd = 0; dd < 16; ++dd) {
                const float4 kv = *(const float4*)&Kl[j][4*dd];
                p0 = fmaf(qr[4*dd+0], kv.x, p0);
                p1 = fmaf(qr[4*dd+1], kv.y, p1);
                p2 = fmaf(qr[4*dd+2], kv.z, p2);
                p3 = fmaf(qr[4*dd+3], kv.w, p3);
            }
            const float s = ((p0 + p1) + (p2 + p3)) * scale;
            float p;
            if (s > m) {
                const float alpha = __expf(m - s);
                l *= alpha;
                #pragma unroll
                for (int d = 0; d < 64; ++d) o[d] *= alpha;
                m = s;
                p = 1.f;
            } else {
                p = __expf(s - m);
            }
            l += p;
            #pragma unroll
            for (int dd = 0; dd < 16; ++dd) {
                const float4 vv = *(const float4*)&Vl[j][4*dd];
                o[4*dd+0] = fmaf(p, vv.x, o[4*dd+0]);
                o[4*dd+1] = fmaf(p, vv.y, o[4*dd+1]);
                o[4*dd+2] = fmaf(p, vv.z, o[4*dd+2]);
                o[4*dd+3] = fmaf(p, vv.w, o[4*dd+3]);
            }
        }
        __syncthreads();
    }

    const float inv = 1.f / l;
    float* yp = y + base + (size_t)qrow * EMB;
    #pragma unroll
    for (int i = 0; i < 16; ++i) {
        float4 o4;
        o4.x = o[4*i+0] * inv; o4.y = o[4*i+1] * inv;
        o4.z = o[4*i+2] * inv; o4.w = o[4*i+3] * inv;
        *(float4*)(yp + 4*i) = o4;
    }
}

// ---------------------------------------------------------------------------
extern "C" void kernel_launch(void* const* d_in, const int* in_sizes, int n_in,
                              void* d_out, int out_size, void* d_ws, size_t ws_size,
                              hipStream_t stream) {
    const int*   idx   = (const int*)  d_in[0];
    const float* tok   = (const float*)d_in[1];
    const float* pos   = (const float*)d_in[2];
    const float* Wq    = (const float*)d_in[3];
    const float* Wk    = (const float*)d_in[4];
    const float* Wv    = (const float*)d_in[5];
    const float* Wproj = (const float*)d_in[6];
    const float* bproj = (const float*)d_in[7];
    const float* ln1g  = (const float*)d_in[8];
    const float* ln1b  = (const float*)d_in[9];
    const float* W1    = (const float*)d_in[10];
    const float* b1    = (const float*)d_in[11];
    const float* W2    = (const float*)d_in[12];
    const float* b2    = (const float*)d_in[13];
    const float* ln2g  = (const float*)d_in[14];
    const float* ln2b  = (const float*)d_in[15];
    const float* Wlm   = (const float*)d_in[16];
    const float* blm   = (const float*)d_in[17];
    float* out = (float*)d_out;

    // workspace layout (floats): x | h | q | k | v | y ; hid reuses q..y
    float* x  = (float*)d_ws;
    float* hb = x  + (size_t)BT * EMB;
    float* qb = hb + (size_t)BT * EMB;
    float* kb = qb + (size_t)BT * EMB;
    float* vb = kb + (size_t)BT * EMB;
    float* yb = vb + (size_t)BT * EMB;
    float* hid = qb;   // 8192*1024 floats = q..y region (32 MB), dead by then

    embed_kernel<<<BT, 64, 0, stream>>>(idx, tok, pos, x);

    const dim3 gE(EMB / 64, BT / 64);          // 4 x 128
    const dim3 gH(1024 / 64, BT / 64);         // 16 x 128
    const dim3 gV(VOCAB / 64, BT / 64);        // 500 x 128
    const dim3 gA(TBLK / 64, BATCH * NHEAD);   // 32 x 16

    for (int l = 0; l < NLAYER; ++l) {
        ln_kernel<<<BT, 64, 0, stream>>>(x, ln1g + l * EMB, ln1b + l * EMB, hb);
        gemm_kernel<0,0,0><<<gE, 256, 0, stream>>>(hb, Wq + (size_t)l*EMB*EMB, nullptr, nullptr, qb, BT, EMB, EMB);
        gemm_kernel<0,0,0><<<gE, 256, 0, stream>>>(hb, Wk + (size_t)l*EMB*EMB, nullptr, nullptr, kb, BT, EMB, EMB);
        gemm_kernel<0,0,0><<<gE, 256, 0, stream>>>(hb, Wv + (size_t)l*EMB*EMB, nullptr, nullptr, vb, BT, EMB, EMB);
        attn_kernel<<<gA, 64, 0, stream>>>(qb, kb, vb, yb);
        gemm_kernel<1,1,0><<<gE, 256, 0, stream>>>(yb, Wproj + (size_t)l*EMB*EMB, bproj + l*EMB, x, x, BT, EMB, EMB);
        ln_kernel<<<BT, 64, 0, stream>>>(x, ln2g + l * EMB, ln2b + l * EMB, hb);
        gemm_kernel<1,0,1><<<gH, 256, 0, stream>>>(hb, W1 + (size_t)l*EMB*4*EMB, b1 + l*4*EMB, nullptr, hid, BT, 4*EMB, EMB);
        gemm_kernel<1,1,0><<<gE, 256, 0, stream>>>(hid, W2 + (size_t)l*4*EMB*EMB, b2 + l*EMB, x, x, BT, EMB, 4*EMB);
    }

    gemm_kernel<1,0,0><<<gV, 256, 0, stream>>>(x, Wlm, blm, nullptr, out, BT, VOCAB, EMB);
}

// Round 2
// 838.916 us; speedup vs baseline: 7.6964x; 7.6964x over previous
//
#include <hip/hip_runtime.h>
#include <hip/hip_bf16.h>

#define EMB 256
#define NHEAD 4
#define HSZ 64
#define NLAYER 3
#define TBLK 2048
#define VOCAB 32000
#define BATCH 4
#define LNEPS 1e-5f
#define BT (BATCH * TBLK)   // 8192 rows
#define QKVD (3 * EMB)      // 768

typedef __attribute__((ext_vector_type(8))) short bf16x8v;  // 8 bf16 (4 VGPRs)
typedef __attribute__((ext_vector_type(4))) float f32x4;
typedef unsigned short u16;
typedef unsigned int u32;

// round-to-nearest-even f32 -> bf16 bits
__device__ __forceinline__ u16 f2bf(float f) {
    union { float f; u32 u; } c; c.f = f;
    u32 r = c.u + 0x7fff + ((c.u >> 16) & 1);
    return (u16)(r >> 16);
}
__device__ __forceinline__ u32 pack2(float a, float b) {
    return (u32)f2bf(a) | ((u32)f2bf(b) << 16);
}

// ---------------------------------------------------------------------------
// Embedding: x[row,:] = tok[idx[row],:] + pos[row%T,:]   (fp32 residual stream)
// ---------------------------------------------------------------------------
__global__ __launch_bounds__(64) void embed_kernel(
    const int* __restrict__ idx, const float* __restrict__ tok,
    const float* __restrict__ pos, float* __restrict__ x)
{
    const int row = blockIdx.x;
    const int t = row & (TBLK - 1);
    const int token = idx[row];
    const int e = threadIdx.x * 4;
    const float4 tv = *(const float4*)&tok[(size_t)token * EMB + e];
    const float4 pv = *(const float4*)&pos[(size_t)t * EMB + e];
    float4 o;
    o.x = tv.x + pv.x; o.y = tv.y + pv.y; o.z = tv.z + pv.z; o.w = tv.w + pv.w;
    *(float4*)&x[(size_t)row * EMB + e] = o;
}

// ---------------------------------------------------------------------------
// LayerNorm (population var) fp32 in -> bf16 out. One wave per row.
// ---------------------------------------------------------------------------
__global__ __launch_bounds__(64) void ln_kernel(
    const float* __restrict__ x, const float* __restrict__ g,
    const float* __restrict__ b, u16* __restrict__ out)
{
    const int row = blockIdx.x;
    const int e = threadIdx.x * 4;
    const float4 xv = *(const float4*)&x[(size_t)row * EMB + e];
    float s1 = xv.x + xv.y + xv.z + xv.w;
    float s2 = xv.x * xv.x + xv.y * xv.y + xv.z * xv.z + xv.w * xv.w;
    #pragma unroll
    for (int off = 32; off >= 1; off >>= 1) {
        s1 += __shfl_xor(s1, off);
        s2 += __shfl_xor(s2, off);
    }
    const float mu  = s1 * (1.0f / EMB);
    const float var = s2 * (1.0f / EMB) - mu * mu;
    const float rs  = rsqrtf(var + LNEPS);
    const float4 gv = *(const float4*)&g[e];
    const float4 bv = *(const float4*)&b[e];
    ushort4 o;
    o.x = f2bf((xv.x - mu) * rs * gv.x + bv.x);
    o.y = f2bf((xv.y - mu) * rs * gv.y + bv.y);
    o.z = f2bf((xv.z - mu) * rs * gv.z + bv.z);
    o.w = f2bf((xv.w - mu) * rs * gv.w + bv.w);
    *(ushort4*)&out[(size_t)row * EMB + e] = o;
}

// ---------------------------------------------------------------------------
// f32 -> bf16 cast (for final x before LM head)
// ---------------------------------------------------------------------------
__global__ __launch_bounds__(256) void cast_kernel(
    const float* __restrict__ in, u16* __restrict__ out)
{
    const int i = (blockIdx.x * 256 + threadIdx.x) * 4;
    const float4 v = *(const float4*)&in[i];
    ushort4 o; o.x = f2bf(v.x); o.y = f2bf(v.y); o.z = f2bf(v.z); o.w = f2bf(v.w);
    *(ushort4*)&out[i] = o;
}

// ---------------------------------------------------------------------------
// Transpose + cast: W [K][N] f32 -> Wt [N][K] bf16. 32x32 tiles, block 32x8.
// ---------------------------------------------------------------------------
__global__ __launch_bounds__(256) void transpose_cast(
    const float* __restrict__ W, u16* __restrict__ Wt, int K, int N)
{
    __shared__ float t[32][33];
    const int bx = blockIdx.x, by = blockIdx.y;
    const int tx = threadIdx.x, ty = threadIdx.y;
    #pragma unroll
    for (int i = 0; i < 32; i += 8)
        t[ty + i][tx] = W[(size_t)(by * 32 + ty + i) * N + bx * 32 + tx];
    __syncthreads();
    #pragma unroll
    for (int i = 0; i < 32; i += 8)
        Wt[(size_t)(bx * 32 + ty + i) * K + by * 32 + tx] = f2bf(t[tx][ty + i]);
}

// ---------------------------------------------------------------------------
// MFMA GEMM: C[M,N] = A[M,K](bf16) @ Bt[N,K](bf16)^T, fp32 accum.
// 128x128 tile, BK=32, 256 thr = 4 waves (2x2 of 64x64), 4x4 frags of 16x16x32.
// LDS rows padded to 40 bf16 (80B = 20 words; stride-20 reads are 2-way = free).
// ---------------------------------------------------------------------------
template<int BIAS, int RES, int RELU, int OUTBF>
__global__ __launch_bounds__(256) void mgemm(
    const u16* __restrict__ A, const u16* __restrict__ Bt,
    const float* __restrict__ bias, const float* __restrict__ res,
    void* __restrict__ Cv, int M, int N, int K)
{
    constexpr int LDW = 40;
    __shared__ u16 Al[128 * LDW];
    __shared__ u16 Bl[128 * LDW];
    const int tid = threadIdx.x;
    const int bn = blockIdx.x, bm = blockIdx.y;
    const int wid = tid >> 6, lane = tid & 63;
    const int wr = (wid >> 1) * 64, wc = (wid & 1) * 64;
    const int fr = lane & 15, fq = lane >> 4;
    const int sr = tid >> 1, sk = (tid & 1) * 16;

    const u16* Ag = A + (size_t)(bm * 128 + sr) * K + sk;
    const u16* Bg = Bt + (size_t)(bn * 128 + sr) * K + sk;
    u16* Alw = &Al[sr * LDW + sk];
    u16* Blw = &Bl[sr * LDW + sk];

    f32x4 acc[4][4];
    #pragma unroll
    for (int i = 0; i < 4; ++i)
        #pragma unroll
        for (int j = 0; j < 4; ++j)
            acc[i][j] = f32x4{0.f, 0.f, 0.f, 0.f};

    for (int k0 = 0; k0 < K; k0 += 32) {
        const bf16x8v a0 = *(const bf16x8v*)(Ag + k0);
        const bf16x8v a1 = *(const bf16x8v*)(Ag + k0 + 8);
        const bf16x8v b0 = *(const bf16x8v*)(Bg + k0);
        const bf16x8v b1 = *(const bf16x8v*)(Bg + k0 + 8);
        *(bf16x8v*)Alw = a0; *(bf16x8v*)(Alw + 8) = a1;
        *(bf16x8v*)Blw = b0; *(bf16x8v*)(Blw + 8) = b1;
        __syncthreads();
        bf16x8v af[4], bfr[4];
        #pragma unroll
        for (int mi = 0; mi < 4; ++mi)
            af[mi] = *(const bf16x8v*)&Al[(wr + mi * 16 + fr) * LDW + fq * 8];
        #pragma unroll
        for (int ni = 0; ni < 4; ++ni)
            bfr[ni] = *(const bf16x8v*)&Bl[(wc + ni * 16 + fr) * LDW + fq * 8];
        #pragma unroll
        for (int mi = 0; mi < 4; ++mi)
            #pragma unroll
            for (int ni = 0; ni < 4; ++ni)
                acc[mi][ni] = __builtin_amdgcn_mfma_f32_16x16x32_bf16(
                    af[mi], bfr[ni], acc[mi][ni], 0, 0, 0);
        __syncthreads();
    }

    float* Cf = (float*)Cv;
    u16*   Cb = (u16*)Cv;
    #pragma unroll
    for (int mi = 0; mi < 4; ++mi) {
        #pragma unroll
        for (int j = 0; j < 4; ++j) {
            const int r = bm * 128 + wr + mi * 16 + fq * 4 + j;
            #pragma unroll
            for (int ni = 0; ni < 4; ++ni) {
                const int c = bn * 128 + wc + ni * 16 + fr;
                float v = acc[mi][ni][j];
                if (BIAS) v += bias[c];
                if (RELU) v = fmaxf(v, 0.f);
                if (RES)  v += res[(size_t)r * N + c];
                if (OUTBF) Cb[(size_t)r * N + c] = f2bf(v);
                else       Cf[(size_t)r * N + c] = v;
            }
        }
    }
}

// ---------------------------------------------------------------------------
// MFMA causal flash attention (bf16 in/out, fp32 softmax/accum).
// Swapped QK^T: S^T = mfma(K, Q) so each q-row lives on the lane-col axis
// (softmax = 2 shfl_xor), P moves to the PV B-operand via register shuffles.
// Block: 256 thr = 4 waves; wave w owns q rows [qt*64+w*16, +16). KVBLK=64.
// K staged row-major LDS, V staged TRANSPOSED [hs][kv] for the PV A-operand.
// qt reversed across blocks for causal load balance. scale = 1/sqrt(E)=1/16.
// ---------------------------------------------------------------------------
__global__ __launch_bounds__(256) void attn_kernel(
    const u16* __restrict__ qkv, u16* __restrict__ y)
{
    constexpr int LDK = 72;   // padded row (144B = 36 words; stride-36 reads 2-way)
    __shared__ u16 Kl[64 * LDK];
    __shared__ u16 Vt[64 * LDK];

    const int tid = threadIdx.x;
    const int qt = (int)gridDim.x - 1 - (int)blockIdx.x;
    const int bh = blockIdx.y;
    const int b = bh >> 2, h = bh & 3;
    const int w = tid >> 6, lane = tid & 63;
    const int fr = lane & 15, fq = lane >> 4;
    const size_t rowbase = (size_t)b * TBLK;
    const int qoff = h * HSZ, koff = EMB + h * HSZ, voff = 2 * EMB + h * HSZ;
    const int qg = qt * 64 + w * 16 + fr;       // this lane's q row
    const int wqmax = qt * 64 + w * 16 + 15;    // wave's max q row

    bf16x8v qf[2];
    #pragma unroll
    for (int ks = 0; ks < 2; ++ks)
        qf[ks] = *(const bf16x8v*)&qkv[(rowbase + qg) * QKVD + qoff + ks * 32 + fq * 8];

    f32x4 yac[4];
    #pragma unroll
    for (int mi = 0; mi < 4; ++mi) yac[mi] = f32x4{0.f, 0.f, 0.f, 0.f};
    float m = -1e30f, l = 0.f;

    const int skv = tid >> 2, sc = (tid & 3) * 16;

    for (int kv0 = 0; kv0 <= qt * 64; kv0 += 64) {
        {   // stage K row-major, V transposed
            const u16* kp = &qkv[(rowbase + kv0 + skv) * QKVD + koff + sc];
            *(bf16x8v*)&Kl[skv * LDK + sc]     = *(const bf16x8v*)kp;
            *(bf16x8v*)&Kl[skv * LDK + sc + 8] = *(const bf16x8v*)(kp + 8);
            const u16* vp = &qkv[(rowbase + kv0 + skv) * QKVD + voff + sc];
            const bf16x8v v0 = *(const bf16x8v*)vp;
            const bf16x8v v1 = *(const bf16x8v*)(vp + 8);
            #pragma unroll
            for (int i = 0; i < 8; ++i) Vt[(sc + i) * LDK + skv] = (u16)v0[i];
            #pragma unroll
            for (int i = 0; i < 8; ++i) Vt[(sc + 8 + i) * LDK + skv] = (u16)v1[i];
        }
        __syncthreads();

        if (kv0 <= wqmax) {
            // S^T = K @ Q : frag mb covers kv rows mb*16..+16, lane col = q row fr
            f32x4 st[4];
            #pragma unroll
            for (int mb = 0; mb < 4; ++mb) {
                st[mb] = f32x4{0.f, 0.f, 0.f, 0.f};
                #pragma unroll
                for (int ks = 0; ks < 2; ++ks) {
                    const bf16x8v kf = *(const bf16x8v*)
                        &Kl[(mb * 16 + fr) * LDK + ks * 32 + fq * 8];
                    st[mb] = __builtin_amdgcn_mfma_f32_16x16x32_bf16(
                        kf, qf[ks], st[mb], 0, 0, 0);
                }
            }
            // mask + online softmax (lane holds kv = kv0+mb*16+fq*4+j for q=qg)
            float p[4][4];
            float mloc = -1e30f;
            #pragma unroll
            for (int mb = 0; mb < 4; ++mb)
                #pragma unroll
                for (int j = 0; j < 4; ++j) {
                    const int kvg = kv0 + mb * 16 + fq * 4 + j;
                    const float s = (kvg <= qg) ? st[mb][j] * 0.0625f : -1e30f;
                    p[mb][j] = s;
                    mloc = fmaxf(mloc, s);
                }
            mloc = fmaxf(mloc, __shfl_xor(mloc, 16));
            mloc = fmaxf(mloc, __shfl_xor(mloc, 32));
            const float mnew = fmaxf(m, mloc);
            const float alpha = __expf(m - mnew);
            float rsum = 0.f;
            #pragma unroll
            for (int mb = 0; mb < 4; ++mb)
                #pragma unroll
                for (int j = 0; j < 4; ++j) {
                    p[mb][j] = __expf(p[mb][j] - mnew);
                    rsum += p[mb][j];
                }
            rsum += __shfl_xor(rsum, 16);
            rsum += __shfl_xor(rsum, 32);
            l = l * alpha + rsum;
            m = mnew;
            #pragma unroll
            for (int mi = 0; mi < 4; ++mi) yac[mi] *= alpha;

            // pack P to bf16 pairs: pk[mb][h] = {p[2h], p[2h+1]}
            u32 pk[4][2];
            #pragma unroll
            for (int mb = 0; mb < 4; ++mb) {
                pk[mb][0] = pack2(p[mb][0], p[mb][1]);
                pk[mb][1] = pack2(p[mb][2], p[mb][3]);
            }
            // y^T += V^T @ P^T ; build P^T B-frags by register shuffle:
            // target lane (fq,fr) k-chunk kv = ksv*32 + fq*8 + t*2{+1}
            #pragma unroll
            for (int ksv = 0; ksv < 2; ++ksv) {
                union { u32 u[4]; bf16x8v v; } pf;
                #pragma unroll
                for (int t = 0; t < 4; ++t) {
                    const int srcl = ((fq & 1) * 2 + (t >> 1)) * 16 + fr;
                    const u32 lo = __shfl(pk[ksv * 2 + 0][t & 1], srcl);
                    const u32 hi = __shfl(pk[ksv * 2 + 1][t & 1], srcl);
                    pf.u[t] = (fq >> 1) ? hi : lo;
                }
                #pragma unroll
                for (int mi = 0; mi < 4; ++mi) {
                    const bf16x8v vf = *(const bf16x8v*)
                        &Vt[(mi * 16 + fr) * LDK + ksv * 32 + fq * 8];
                    yac[mi] = __builtin_amdgcn_mfma_f32_16x16x32_bf16(
                        vf, pf.v, yac[mi], 0, 0, 0);
                }
            }
        }
        __syncthreads();
    }

    // y^T C-layout: row = hs = mi*16+fq*4+j (j consecutive -> ushort4), col = q = fr
    const float inv = 1.f / l;
    #pragma unroll
    for (int mi = 0; mi < 4; ++mi) {
        ushort4 o;
        o.x = f2bf(yac[mi][0] * inv);
        o.y = f2bf(yac[mi][1] * inv);
        o.z = f2bf(yac[mi][2] * inv);
        o.w = f2bf(yac[mi][3] * inv);
        *(ushort4*)&y[(rowbase + qg) * EMB + h * HSZ + mi * 16 + fq * 4] = o;
    }
}

// ---------------------------------------------------------------------------
extern "C" void kernel_launch(void* const* d_in, const int* in_sizes, int n_in,
                              void* d_out, int out_size, void* d_ws, size_t ws_size,
                              hipStream_t stream) {
    const int*   idx   = (const int*)  d_in[0];
    const float* tok   = (const float*)d_in[1];
    const float* pos   = (const float*)d_in[2];
    const float* Wq    = (const float*)d_in[3];
    const float* Wk    = (const float*)d_in[4];
    const float* Wv    = (const float*)d_in[5];
    const float* Wproj = (const float*)d_in[6];
    const float* bproj = (const float*)d_in[7];
    const float* ln1g  = (const float*)d_in[8];
    const float* ln1b  = (const float*)d_in[9];
    const float* W1    = (const float*)d_in[10];
    const float* b1    = (const float*)d_in[11];
    const float* W2    = (const float*)d_in[12];
    const float* b2    = (const float*)d_in[13];
    const float* ln2g  = (const float*)d_in[14];
    const float* ln2b  = (const float*)d_in[15];
    const float* Wlm   = (const float*)d_in[16];
    const float* blm   = (const float*)d_in[17];
    float* out = (float*)d_out;

    // workspace: x(f32) | hb | qkv | yb | transposed bf16 weights
    float* x    = (float*)d_ws;
    u16*   hb   = (u16*)(x + (size_t)BT * EMB);
    u16*   qkvb = hb + (size_t)BT * EMB;
    u16*   yb   = qkvb + (size_t)BT * QKVD;
    u16*   hid  = qkvb;  // [BT][1024] aliases qkv+yb (dead when MLP runs)
    u16*   Wqkvt  = yb + (size_t)BT * EMB;
    u16*   Wprojt = Wqkvt  + (size_t)NLAYER * QKVD * EMB;
    u16*   W1t    = Wprojt + (size_t)NLAYER * EMB * EMB;
    u16*   W2t    = W1t    + (size_t)NLAYER * EMB * 4 * EMB;
    u16*   Wlmt   = W2t    + (size_t)NLAYER * 4 * EMB * EMB;

    const dim3 tb(32, 8);
    for (int l = 0; l < NLAYER; ++l) {
        transpose_cast<<<dim3(8, 8),  tb, 0, stream>>>(Wq + (size_t)l*EMB*EMB,   Wqkvt + (size_t)l*QKVD*EMB,             EMB, EMB);
        transpose_cast<<<dim3(8, 8),  tb, 0, stream>>>(Wk + (size_t)l*EMB*EMB,   Wqkvt + (size_t)l*QKVD*EMB + EMB*EMB,   EMB, EMB);
        transpose_cast<<<dim3(8, 8),  tb, 0, stream>>>(Wv + (size_t)l*EMB*EMB,   Wqkvt + (size_t)l*QKVD*EMB + 2*EMB*EMB, EMB, EMB);
        transpose_cast<<<dim3(8, 8),  tb, 0, stream>>>(Wproj + (size_t)l*EMB*EMB, Wprojt + (size_t)l*EMB*EMB,            EMB, EMB);
        transpose_cast<<<dim3(32, 8), tb, 0, stream>>>(W1 + (size_t)l*EMB*4*EMB, W1t + (size_t)l*EMB*4*EMB,              EMB, 4*EMB);
        transpose_cast<<<dim3(8, 32), tb, 0, stream>>>(W2 + (size_t)l*EMB*4*EMB, W2t + (size_t)l*EMB*4*EMB,              4*EMB, EMB);
    }
    transpose_cast<<<dim3(VOCAB/32, 8), tb, 0, stream>>>(Wlm, Wlmt, EMB, VOCAB);

    embed_kernel<<<BT, 64, 0, stream>>>(idx, tok, pos, x);

    for (int l = 0; l < NLAYER; ++l) {
        ln_kernel<<<BT, 64, 0, stream>>>(x, ln1g + l*EMB, ln1b + l*EMB, hb);
        mgemm<0,0,0,1><<<dim3(QKVD/128, BT/128), 256, 0, stream>>>(
            hb, Wqkvt + (size_t)l*QKVD*EMB, nullptr, nullptr, qkvb, BT, QKVD, EMB);
        attn_kernel<<<dim3(TBLK/64, BATCH*NHEAD), 256, 0, stream>>>(qkvb, yb);
        mgemm<1,1,0,0><<<dim3(EMB/128, BT/128), 256, 0, stream>>>(
            yb, Wprojt + (size_t)l*EMB*EMB, bproj + l*EMB, x, x, BT, EMB, EMB);
        ln_kernel<<<BT, 64, 0, stream>>>(x, ln2g + l*EMB, ln2b + l*EMB, hb);
        mgemm<1,0,1,1><<<dim3(4*EMB/128, BT/128), 256, 0, stream>>>(
            hb, W1t + (size_t)l*EMB*4*EMB, b1 + l*4*EMB, nullptr, hid, BT, 4*EMB, EMB);
        mgemm<1,1,0,0><<<dim3(EMB/128, BT/128), 256, 0, stream>>>(
            hid, W2t + (size_t)l*EMB*4*EMB, b2 + l*EMB, x, x, BT, EMB, 4*EMB);
    }

    cast_kernel<<<BT*EMB/1024, 256, 0, stream>>>(x, hb);
    mgemm<1,0,0,0><<<dim3(VOCAB/128, BT/128), 256, 0, stream>>>(
        hb, Wlmt, blm, nullptr, out, BT, VOCAB, EMB);
}

// Round 3
// 710.410 us; speedup vs baseline: 9.0885x; 1.1809x over previous
//
#include <hip/hip_runtime.h>
#include <hip/hip_bf16.h>

#define EMB 256
#define NHEAD 4
#define HSZ 64
#define NLAYER 3
#define TBLK 2048
#define VOCAB 32000
#define BATCH 4
#define LNEPS 1e-5f
#define BT (BATCH * TBLK)   // 8192 rows
#define QKVD (3 * EMB)      // 768

typedef __attribute__((ext_vector_type(8))) short bf16x8v;  // 8 bf16 (4 VGPRs)
typedef __attribute__((ext_vector_type(4))) float f32x4;
typedef unsigned short u16;
typedef unsigned int u32;

// round-to-nearest-even f32 -> bf16 bits
__device__ __forceinline__ u16 f2bf(float f) {
    union { float f; u32 u; } c; c.f = f;
    u32 r = c.u + 0x7fff + ((c.u >> 16) & 1);
    return (u16)(r >> 16);
}
__device__ __forceinline__ u32 pack2(float a, float b) {
    return (u32)f2bf(a) | ((u32)f2bf(b) << 16);
}

// ---------------------------------------------------------------------------
// Embedding: x[row,:] = tok[idx[row],:] + pos[row%T,:]   (fp32 residual stream)
// ---------------------------------------------------------------------------
__global__ __launch_bounds__(64) void embed_kernel(
    const int* __restrict__ idx, const float* __restrict__ tok,
    const float* __restrict__ pos, float* __restrict__ x)
{
    const int row = blockIdx.x;
    const int t = row & (TBLK - 1);
    const int token = idx[row];
    const int e = threadIdx.x * 4;
    const float4 tv = *(const float4*)&tok[(size_t)token * EMB + e];
    const float4 pv = *(const float4*)&pos[(size_t)t * EMB + e];
    float4 o;
    o.x = tv.x + pv.x; o.y = tv.y + pv.y; o.z = tv.z + pv.z; o.w = tv.w + pv.w;
    *(float4*)&x[(size_t)row * EMB + e] = o;
}

// ---------------------------------------------------------------------------
// LayerNorm (population var) fp32 in -> bf16 out. One wave per row.
// ---------------------------------------------------------------------------
__global__ __launch_bounds__(64) void ln_kernel(
    const float* __restrict__ x, const float* __restrict__ g,
    const float* __restrict__ b, u16* __restrict__ out)
{
    const int row = blockIdx.x;
    const int e = threadIdx.x * 4;
    const float4 xv = *(const float4*)&x[(size_t)row * EMB + e];
    float s1 = xv.x + xv.y + xv.z + xv.w;
    float s2 = xv.x * xv.x + xv.y * xv.y + xv.z * xv.z + xv.w * xv.w;
    #pragma unroll
    for (int off = 32; off >= 1; off >>= 1) {
        s1 += __shfl_xor(s1, off);
        s2 += __shfl_xor(s2, off);
    }
    const float mu  = s1 * (1.0f / EMB);
    const float var = s2 * (1.0f / EMB) - mu * mu;
    const float rs  = rsqrtf(var + LNEPS);
    const float4 gv = *(const float4*)&g[e];
    const float4 bv = *(const float4*)&b[e];
    ushort4 o;
    o.x = f2bf((xv.x - mu) * rs * gv.x + bv.x);
    o.y = f2bf((xv.y - mu) * rs * gv.y + bv.y);
    o.z = f2bf((xv.z - mu) * rs * gv.z + bv.z);
    o.w = f2bf((xv.w - mu) * rs * gv.w + bv.w);
    *(ushort4*)&out[(size_t)row * EMB + e] = o;
}

// ---------------------------------------------------------------------------
// f32 -> bf16 cast (for final x before LM head)
// ---------------------------------------------------------------------------
__global__ __launch_bounds__(256) void cast_kernel(
    const float* __restrict__ in, u16* __restrict__ out)
{
    const int i = (blockIdx.x * 256 + threadIdx.x) * 4;
    const float4 v = *(const float4*)&in[i];
    ushort4 o; o.x = f2bf(v.x); o.y = f2bf(v.y); o.z = f2bf(v.z); o.w = f2bf(v.w);
    *(ushort4*)&out[i] = o;
}

// ---------------------------------------------------------------------------
// Transpose + cast: W [K][N] f32 -> Wt [N][K] bf16, batched over layers (z).
// ---------------------------------------------------------------------------
__global__ __launch_bounds__(256) void transpose_cast(
    const float* __restrict__ W, u16* __restrict__ Wt, int K, int N,
    size_t sW, size_t sWt)
{
    __shared__ float t[32][33];
    W  += (size_t)blockIdx.z * sW;
    Wt += (size_t)blockIdx.z * sWt;
    const int bx = blockIdx.x, by = blockIdx.y;
    const int tx = threadIdx.x, ty = threadIdx.y;
    #pragma unroll
    for (int i = 0; i < 32; i += 8)
        t[ty + i][tx] = W[(size_t)(by * 32 + ty + i) * N + bx * 32 + tx];
    __syncthreads();
    #pragma unroll
    for (int i = 0; i < 32; i += 8)
        Wt[(size_t)(bx * 32 + ty + i) * K + by * 32 + tx] = f2bf(t[tx][ty + i]);
}

// ---------------------------------------------------------------------------
// MFMA GEMM: C[M,N] = A[M,K](bf16) @ Bt[N,K](bf16)^T, fp32 accum.
// 128xBNT tile, BK=32, 256 thr = 4 waves. Double-buffered LDS (1 barrier/iter)
// + register prefetch of tile k+1 issued before the MFMA cluster.
// BNT=128: waves 2x2 (64x64 each). BNT=64: waves 4x1 (32x64 each).
// bm is blockIdx.x (fastest): XCD = bm%8 stable -> A panels pinned per-XCD L2.
// LDS rows padded to 40 bf16 (stride-20-word reads = 2-way = free).
// ---------------------------------------------------------------------------
template<int BNT, int BIAS, int RES, int RELU, int OUTBF>
__global__ __launch_bounds__(256) void mgemm(
    const u16* __restrict__ A, const u16* __restrict__ Bt,
    const float* __restrict__ bias, const float* __restrict__ res,
    void* __restrict__ Cv, int M, int N, int K)
{
    constexpr int LDW = 40;
    constexpr int MI = (BNT == 128) ? 4 : 2;
    __shared__ u16 Al[2][128 * LDW];
    __shared__ u16 Bl[2][BNT * LDW];
    const int tid = threadIdx.x;
    const int bm = blockIdx.x, bn = blockIdx.y;
    const int wid = tid >> 6, lane = tid & 63;
    const int wr = (BNT == 128) ? (wid >> 1) * 64 : wid * 32;
    const int wc = (BNT == 128) ? (wid & 1) * 64 : 0;
    const int fr = lane & 15, fq = lane >> 4;

    // staging indices: A 128x32, B BNTx32
    const int sra = tid >> 1,                       ska = (tid & 1) * 16;
    const int srb = (BNT == 128) ? (tid >> 1) : (tid >> 2);
    const int skb = (BNT == 128) ? (tid & 1) * 16 : (tid & 3) * 8;

    const u16* Ag = A + (size_t)(bm * 128 + sra) * K + ska;
    const u16* Bg = Bt + (size_t)(bn * BNT + srb) * K + skb;

    bf16x8v a0 = *(const bf16x8v*)Ag;
    bf16x8v a1 = *(const bf16x8v*)(Ag + 8);
    bf16x8v b0 = *(const bf16x8v*)Bg;
    bf16x8v b1 = (BNT == 128) ? *(const bf16x8v*)(Bg + 8) : b0;

    f32x4 acc[MI][4];
    #pragma unroll
    for (int i = 0; i < MI; ++i)
        #pragma unroll
        for (int j = 0; j < 4; ++j)
            acc[i][j] = f32x4{0.f, 0.f, 0.f, 0.f};

    int buf = 0;
    for (int k0 = 0; k0 < K; k0 += 32, buf ^= 1) {
        u16* Aw = &Al[buf][sra * LDW + ska];
        *(bf16x8v*)Aw = a0; *(bf16x8v*)(Aw + 8) = a1;
        u16* Bw = &Bl[buf][srb * LDW + skb];
        *(bf16x8v*)Bw = b0;
        if (BNT == 128) *(bf16x8v*)(Bw + 8) = b1;
        __syncthreads();
        if (k0 + 32 < K) {      // prefetch next K-tile; latency hides under MFMA
            a0 = *(const bf16x8v*)(Ag + k0 + 32);
            a1 = *(const bf16x8v*)(Ag + k0 + 40);
            b0 = *(const bf16x8v*)(Bg + k0 + 32);
            if (BNT == 128) b1 = *(const bf16x8v*)(Bg + k0 + 40);
        }
        bf16x8v af[MI], bfr[4];
        #pragma unroll
        for (int mi = 0; mi < MI; ++mi)
            af[mi] = *(const bf16x8v*)&Al[buf][(wr + mi * 16 + fr) * LDW + fq * 8];
        #pragma unroll
        for (int ni = 0; ni < 4; ++ni)
            bfr[ni] = *(const bf16x8v*)&Bl[buf][(wc + ni * 16 + fr) * LDW + fq * 8];
        #pragma unroll
        for (int mi = 0; mi < MI; ++mi)
            #pragma unroll
            for (int ni = 0; ni < 4; ++ni)
                acc[mi][ni] = __builtin_amdgcn_mfma_f32_16x16x32_bf16(
                    af[mi], bfr[ni], acc[mi][ni], 0, 0, 0);
        // no trailing barrier: next iter writes the other buffer
    }

    float* Cf = (float*)Cv;
    u16*   Cb = (u16*)Cv;
    #pragma unroll
    for (int mi = 0; mi < MI; ++mi) {
        #pragma unroll
        for (int j = 0; j < 4; ++j) {
            const int r = bm * 128 + wr + mi * 16 + fq * 4 + j;
            #pragma unroll
            for (int ni = 0; ni < 4; ++ni) {
                const int c = bn * BNT + wc + ni * 16 + fr;
                float v = acc[mi][ni][j];
                if (BIAS) v += bias[c];
                if (RELU) v = fmaxf(v, 0.f);
                if (RES)  v += res[(size_t)r * N + c];
                if (OUTBF) Cb[(size_t)r * N + c] = f2bf(v);
                else       Cf[(size_t)r * N + c] = v;
            }
        }
    }
}

// ---------------------------------------------------------------------------
// MFMA causal flash attention (bf16 in/out, fp32 softmax/accum).
// Swapped QK^T: S^T = mfma(K, Q); softmax = 2 shfl_xor; P -> PV B-operand via
// register shuffles. Double-buffered K/V LDS + register prefetch of next tile.
// Block: 256 thr = 4 waves; wave w owns q rows [qt*64+w*16, +16). KVBLK=64.
// ---------------------------------------------------------------------------
__global__ __launch_bounds__(256) void attn_kernel(
    const u16* __restrict__ qkv, u16* __restrict__ y)
{
    constexpr int LDK = 72;
    __shared__ u16 Kl[2][64 * LDK];
    __shared__ u16 Vt[2][64 * LDK];

    const int tid = threadIdx.x;
    const int qt = (int)gridDim.x - 1 - (int)blockIdx.x;
    const int bh = blockIdx.y;
    const int b = bh >> 2, h = bh & 3;
    const int w = tid >> 6, lane = tid & 63;
    const int fr = lane & 15, fq = lane >> 4;
    const size_t rowbase = (size_t)b * TBLK;
    const int qoff = h * HSZ, koff = EMB + h * HSZ, voff = 2 * EMB + h * HSZ;
    const int qg = qt * 64 + w * 16 + fr;       // this lane's q row

    bf16x8v qf[2];
    #pragma unroll
    for (int ks = 0; ks < 2; ++ks)
        qf[ks] = *(const bf16x8v*)&qkv[(rowbase + qg) * QKVD + qoff + ks * 32 + fq * 8];

    f32x4 yac[4];
    #pragma unroll
    for (int mi = 0; mi < 4; ++mi) yac[mi] = f32x4{0.f, 0.f, 0.f, 0.f};
    float m = -1e30f, l = 0.f;

    const int skv = tid >> 2, sc = (tid & 3) * 16;
    const u16* kbase = &qkv[(rowbase + skv) * QKVD + koff + sc];
    const u16* vbase = &qkv[(rowbase + skv) * QKVD + voff + sc];

    bf16x8v kr0 = *(const bf16x8v*)kbase;
    bf16x8v kr1 = *(const bf16x8v*)(kbase + 8);
    bf16x8v vr0 = *(const bf16x8v*)vbase;
    bf16x8v vr1 = *(const bf16x8v*)(vbase + 8);

    int buf = 0;
    for (int kv0 = 0; kv0 <= qt * 64; kv0 += 64, buf ^= 1) {
        {   // stage from regs: K row-major, V transposed
            u16* Kw = &Kl[buf][skv * LDK + sc];
            *(bf16x8v*)Kw = kr0; *(bf16x8v*)(Kw + 8) = kr1;
            #pragma unroll
            for (int i = 0; i < 8; ++i) Vt[buf][(sc + i) * LDK + skv] = (u16)vr0[i];
            #pragma unroll
            for (int i = 0; i < 8; ++i) Vt[buf][(sc + 8 + i) * LDK + skv] = (u16)vr1[i];
        }
        __syncthreads();
        if (kv0 + 64 <= qt * 64) {   // prefetch next kv tile
            const size_t off = (size_t)(kv0 + 64) * QKVD;
            kr0 = *(const bf16x8v*)(kbase + off);
            kr1 = *(const bf16x8v*)(kbase + off + 8);
            vr0 = *(const bf16x8v*)(vbase + off);
            vr1 = *(const bf16x8v*)(vbase + off + 8);
        }

        // S^T = K @ Q : frag mb covers kv rows mb*16..+16, lane col = q row fr
        f32x4 st[4];
        #pragma unroll
        for (int mb = 0; mb < 4; ++mb) {
            st[mb] = f32x4{0.f, 0.f, 0.f, 0.f};
            #pragma unroll
            for (int ks = 0; ks < 2; ++ks) {
                const bf16x8v kf = *(const bf16x8v*)
                    &Kl[buf][(mb * 16 + fr) * LDK + ks * 32 + fq * 8];
                st[mb] = __builtin_amdgcn_mfma_f32_16x16x32_bf16(
                    kf, qf[ks], st[mb], 0, 0, 0);
            }
        }
        // mask + online softmax (lane holds kv = kv0+mb*16+fq*4+j for q=qg)
        float p[4][4];
        float mloc = -1e30f;
        #pragma unroll
        for (int mb = 0; mb < 4; ++mb)
            #pragma unroll
            for (int j = 0; j < 4; ++j) {
                const int kvg = kv0 + mb * 16 + fq * 4 + j;
                const float s = (kvg <= qg) ? st[mb][j] * 0.0625f : -1e30f;
                p[mb][j] = s;
                mloc = fmaxf(mloc, s);
            }
        mloc = fmaxf(mloc, __shfl_xor(mloc, 16));
        mloc = fmaxf(mloc, __shfl_xor(mloc, 32));
        const float mnew = fmaxf(m, mloc);
        const float alpha = __expf(m - mnew);
        float rsum = 0.f;
        #pragma unroll
        for (int mb = 0; mb < 4; ++mb)
            #pragma unroll
            for (int j = 0; j < 4; ++j) {
                p[mb][j] = __expf(p[mb][j] - mnew);
                rsum += p[mb][j];
            }
        rsum += __shfl_xor(rsum, 16);
        rsum += __shfl_xor(rsum, 32);
        l = l * alpha + rsum;
        m = mnew;
        #pragma unroll
        for (int mi = 0; mi < 4; ++mi) yac[mi] *= alpha;

        // pack P to bf16 pairs: pk[mb][h2] = {p[2h2], p[2h2+1]}
        u32 pk[4][2];
        #pragma unroll
        for (int mb = 0; mb < 4; ++mb) {
            pk[mb][0] = pack2(p[mb][0], p[mb][1]);
            pk[mb][1] = pack2(p[mb][2], p[mb][3]);
        }
        // y^T += V^T @ P^T ; build P^T B-frags by register shuffle
        #pragma unroll
        for (int ksv = 0; ksv < 2; ++ksv) {
            union { u32 u[4]; bf16x8v v; } pf;
            #pragma unroll
            for (int t = 0; t < 4; ++t) {
                const int srcl = ((fq & 1) * 2 + (t >> 1)) * 16 + fr;
                const u32 lo = __shfl(pk[ksv * 2 + 0][t & 1], srcl);
                const u32 hi = __shfl(pk[ksv * 2 + 1][t & 1], srcl);
                pf.u[t] = (fq >> 1) ? hi : lo;
            }
            #pragma unroll
            for (int mi = 0; mi < 4; ++mi) {
                const bf16x8v vf = *(const bf16x8v*)
                    &Vt[buf][(mi * 16 + fr) * LDK + ksv * 32 + fq * 8];
                yac[mi] = __builtin_amdgcn_mfma_f32_16x16x32_bf16(
                    vf, pf.v, yac[mi], 0, 0, 0);
            }
        }
        // no trailing barrier: next iter writes the other buffer
    }

    // y^T C-layout: row = hs = mi*16+fq*4+j (j consecutive), col = q = fr
    const float inv = 1.f / l;
    #pragma unroll
    for (int mi = 0; mi < 4; ++mi) {
        ushort4 o;
        o.x = f2bf(yac[mi][0] * inv);
        o.y = f2bf(yac[mi][1] * inv);
        o.z = f2bf(yac[mi][2] * inv);
        o.w = f2bf(yac[mi][3] * inv);
        *(ushort4*)&y[(rowbase + qg) * EMB + h * HSZ + mi * 16 + fq * 4] = o;
    }
}

// ---------------------------------------------------------------------------
extern "C" void kernel_launch(void* const* d_in, const int* in_sizes, int n_in,
                              void* d_out, int out_size, void* d_ws, size_t ws_size,
                              hipStream_t stream) {
    const int*   idx   = (const int*)  d_in[0];
    const float* tok   = (const float*)d_in[1];
    const float* pos   = (const float*)d_in[2];
    const float* Wq    = (const float*)d_in[3];
    const float* Wk    = (const float*)d_in[4];
    const float* Wv    = (const float*)d_in[5];
    const float* Wproj = (const float*)d_in[6];
    const float* bproj = (const float*)d_in[7];
    const float* ln1g  = (const float*)d_in[8];
    const float* ln1b  = (const float*)d_in[9];
    const float* W1    = (const float*)d_in[10];
    const float* b1    = (const float*)d_in[11];
    const float* W2    = (const float*)d_in[12];
    const float* b2    = (const float*)d_in[13];
    const float* ln2g  = (const float*)d_in[14];
    const float* ln2b  = (const float*)d_in[15];
    const float* Wlm   = (const float*)d_in[16];
    const float* blm   = (const float*)d_in[17];
    float* out = (float*)d_out;

    // workspace: x(f32) | hb | qkv | yb | transposed bf16 weights
    float* x    = (float*)d_ws;
    u16*   hb   = (u16*)(x + (size_t)BT * EMB);
    u16*   qkvb = hb + (size_t)BT * EMB;
    u16*   yb   = qkvb + (size_t)BT * QKVD;
    u16*   hid  = qkvb;  // [BT][1024] aliases qkv+yb (dead when MLP runs)
    u16*   Wqkvt  = yb + (size_t)BT * EMB;
    u16*   Wprojt = Wqkvt  + (size_t)NLAYER * QKVD * EMB;
    u16*   W1t    = Wprojt + (size_t)NLAYER * EMB * EMB;
    u16*   W2t    = W1t    + (size_t)NLAYER * EMB * 4 * EMB;
    u16*   Wlmt   = W2t    + (size_t)NLAYER * 4 * EMB * EMB;

    const dim3 tb(32, 8);
    transpose_cast<<<dim3(8, 8, NLAYER), tb, 0, stream>>>(
        Wq, Wqkvt, EMB, EMB, (size_t)EMB*EMB, (size_t)QKVD*EMB);
    transpose_cast<<<dim3(8, 8, NLAYER), tb, 0, stream>>>(
        Wk, Wqkvt + EMB*EMB, EMB, EMB, (size_t)EMB*EMB, (size_t)QKVD*EMB);
    transpose_cast<<<dim3(8, 8, NLAYER), tb, 0, stream>>>(
        Wv, Wqkvt + 2*EMB*EMB, EMB, EMB, (size_t)EMB*EMB, (size_t)QKVD*EMB);
    transpose_cast<<<dim3(8, 8, NLAYER), tb, 0, stream>>>(
        Wproj, Wprojt, EMB, EMB, (size_t)EMB*EMB, (size_t)EMB*EMB);
    transpose_cast<<<dim3(32, 8, NLAYER), tb, 0, stream>>>(
        W1, W1t, EMB, 4*EMB, (size_t)EMB*4*EMB, (size_t)EMB*4*EMB);
    transpose_cast<<<dim3(8, 32, NLAYER), tb, 0, stream>>>(
        W2, W2t, 4*EMB, EMB, (size_t)4*EMB*EMB, (size_t)4*EMB*EMB);
    transpose_cast<<<dim3(VOCAB/32, 8, 1), tb, 0, stream>>>(
        Wlm, Wlmt, EMB, VOCAB, 0, 0);

    embed_kernel<<<BT, 64, 0, stream>>>(idx, tok, pos, x);

    for (int l = 0; l < NLAYER; ++l) {
        ln_kernel<<<BT, 64, 0, stream>>>(x, ln1g + l*EMB, ln1b + l*EMB, hb);
        mgemm<128,0,0,0,1><<<dim3(BT/128, QKVD/128), 256, 0, stream>>>(
            hb, Wqkvt + (size_t)l*QKVD*EMB, nullptr, nullptr, qkvb, BT, QKVD, EMB);
        attn_kernel<<<dim3(TBLK/64, BATCH*NHEAD), 256, 0, stream>>>(qkvb, yb);
        mgemm<64,1,1,0,0><<<dim3(BT/128, EMB/64), 256, 0, stream>>>(
            yb, Wprojt + (size_t)l*EMB*EMB, bproj + l*EMB, x, x, BT, EMB, EMB);
        ln_kernel<<<BT, 64, 0, stream>>>(x, ln2g + l*EMB, ln2b + l*EMB, hb);
        mgemm<128,1,0,1,1><<<dim3(BT/128, 4*EMB/128), 256, 0, stream>>>(
            hb, W1t + (size_t)l*EMB*4*EMB, b1 + l*4*EMB, nullptr, hid, BT, 4*EMB, EMB);
        mgemm<64,1,1,0,0><<<dim3(BT/128, EMB/64), 256, 0, stream>>>(
            hid, W2t + (size_t)l*4*EMB*EMB, b2 + l*EMB, x, x, BT, EMB, 4*EMB);
    }

    cast_kernel<<<BT*EMB/1024, 256, 0, stream>>>(x, hb);
    mgemm<128,1,0,0,0><<<dim3(BT/128, VOCAB/128), 256, 0, stream>>>(
        hb, Wlmt, blm, nullptr, out, BT, VOCAB, EMB);
}

// Round 4
// 701.009 us; speedup vs baseline: 9.2104x; 1.0134x over previous
//
#include <hip/hip_runtime.h>
#include <hip/hip_bf16.h>

#define EMB 256
#define NHEAD 4
#define HSZ 64
#define NLAYER 3
#define TBLK 2048
#define VOCAB 32000
#define BATCH 4
#define LNEPS 1e-5f
#define BT (BATCH * TBLK)   // 8192 rows
#define QKVD (3 * EMB)      // 768

typedef __attribute__((ext_vector_type(8))) short bf16x8v;  // 8 bf16 (4 VGPRs)
typedef __attribute__((ext_vector_type(4))) float f32x4;
typedef unsigned short u16;
typedef unsigned int u32;

// round-to-nearest-even f32 -> bf16 bits
__device__ __forceinline__ u16 f2bf(float f) {
    union { float f; u32 u; } c; c.f = f;
    u32 r = c.u + 0x7fff + ((c.u >> 16) & 1);
    return (u16)(r >> 16);
}
__device__ __forceinline__ u32 pack2(float a, float b) {
    return (u32)f2bf(a) | ((u32)f2bf(b) << 16);
}

// async global->LDS, 16 bytes per lane (dest must be linear in lane order)
__device__ __forceinline__ void gload16(const u16* g, u16* l) {
    __builtin_amdgcn_global_load_lds(
        (__attribute__((address_space(1))) void*)g,
        (__attribute__((address_space(3))) void*)l, 16, 0, 0);
}

// ---------------------------------------------------------------------------
// Embedding: 4 rows per 256-thr block (one wave per row).
// ---------------------------------------------------------------------------
__global__ __launch_bounds__(256) void embed_kernel(
    const int* __restrict__ idx, const float* __restrict__ tok,
    const float* __restrict__ pos, float* __restrict__ x)
{
    const int row = blockIdx.x * 4 + (threadIdx.x >> 6);
    const int t = row & (TBLK - 1);
    const int token = idx[row];
    const int e = (threadIdx.x & 63) * 4;
    const float4 tv = *(const float4*)&tok[(size_t)token * EMB + e];
    const float4 pv = *(const float4*)&pos[(size_t)t * EMB + e];
    float4 o;
    o.x = tv.x + pv.x; o.y = tv.y + pv.y; o.z = tv.z + pv.z; o.w = tv.w + pv.w;
    *(float4*)&x[(size_t)row * EMB + e] = o;
}

// ---------------------------------------------------------------------------
// LayerNorm (population var) fp32 in -> bf16 out. 4 rows per block.
// ---------------------------------------------------------------------------
__global__ __launch_bounds__(256) void ln_kernel(
    const float* __restrict__ x, const float* __restrict__ g,
    const float* __restrict__ b, u16* __restrict__ out)
{
    const int row = blockIdx.x * 4 + (threadIdx.x >> 6);
    const int e = (threadIdx.x & 63) * 4;
    const float4 xv = *(const float4*)&x[(size_t)row * EMB + e];
    float s1 = xv.x + xv.y + xv.z + xv.w;
    float s2 = xv.x * xv.x + xv.y * xv.y + xv.z * xv.z + xv.w * xv.w;
    #pragma unroll
    for (int off = 32; off >= 1; off >>= 1) {
        s1 += __shfl_xor(s1, off);
        s2 += __shfl_xor(s2, off);
    }
    const float mu  = s1 * (1.0f / EMB);
    const float var = s2 * (1.0f / EMB) - mu * mu;
    const float rs  = rsqrtf(var + LNEPS);
    const float4 gv = *(const float4*)&g[e];
    const float4 bv = *(const float4*)&b[e];
    ushort4 o;
    o.x = f2bf((xv.x - mu) * rs * gv.x + bv.x);
    o.y = f2bf((xv.y - mu) * rs * gv.y + bv.y);
    o.z = f2bf((xv.z - mu) * rs * gv.z + bv.z);
    o.w = f2bf((xv.w - mu) * rs * gv.w + bv.w);
    *(ushort4*)&out[(size_t)row * EMB + e] = o;
}

// ---------------------------------------------------------------------------
// Transpose + cast: W [K][N] f32 -> Wt [N][K] bf16, batched over layers (z).
// ---------------------------------------------------------------------------
__global__ __launch_bounds__(256) void transpose_cast(
    const float* __restrict__ W, u16* __restrict__ Wt, int K, int N,
    size_t sW, size_t sWt)
{
    __shared__ float t[32][33];
    W  += (size_t)blockIdx.z * sW;
    Wt += (size_t)blockIdx.z * sWt;
    const int bx = blockIdx.x, by = blockIdx.y;
    const int tx = threadIdx.x, ty = threadIdx.y;
    #pragma unroll
    for (int i = 0; i < 32; i += 8)
        t[ty + i][tx] = W[(size_t)(by * 32 + ty + i) * N + bx * 32 + tx];
    __syncthreads();
    #pragma unroll
    for (int i = 0; i < 32; i += 8)
        Wt[(size_t)(bx * 32 + ty + i) * K + by * 32 + tx] = f2bf(t[tx][ty + i]);
}

// Fused ExE transposes: z = layer*4 + {Wq,Wk,Wv,Wproj}
__global__ __launch_bounds__(256) void transpose_qkvp(
    const float* __restrict__ Wq, const float* __restrict__ Wk,
    const float* __restrict__ Wv, const float* __restrict__ Wp,
    u16* __restrict__ Wqkvt, u16* __restrict__ Wprojt)
{
    __shared__ float t[32][33];
    const int which = blockIdx.z & 3, l = blockIdx.z >> 2;
    const float* W;
    u16* Wt;
    switch (which) {
        case 0: W = Wq + (size_t)l*EMB*EMB; Wt = Wqkvt + (size_t)l*QKVD*EMB;               break;
        case 1: W = Wk + (size_t)l*EMB*EMB; Wt = Wqkvt + (size_t)l*QKVD*EMB + EMB*EMB;     break;
        case 2: W = Wv + (size_t)l*EMB*EMB; Wt = Wqkvt + (size_t)l*QKVD*EMB + 2*EMB*EMB;   break;
        default:W = Wp + (size_t)l*EMB*EMB; Wt = Wprojt + (size_t)l*EMB*EMB;               break;
    }
    const int bx = blockIdx.x, by = blockIdx.y;
    const int tx = threadIdx.x, ty = threadIdx.y;
    #pragma unroll
    for (int i = 0; i < 32; i += 8)
        t[ty + i][tx] = W[(size_t)(by * 32 + ty + i) * EMB + bx * 32 + tx];
    __syncthreads();
    #pragma unroll
    for (int i = 0; i < 32; i += 8)
        Wt[(size_t)(bx * 32 + ty + i) * EMB + by * 32 + tx] = f2bf(t[tx][ty + i]);
}

// ---------------------------------------------------------------------------
// MFMA GEMM: C[M,N] = A[M,K](bf16) @ Bt[N,K](bf16)^T, fp32 accum.
// 128xBNT tile, BK=32, 256 thr = 4 waves. m97 structure: global_load_lds
// width-16 staging into LINEAR [rows][32] LDS, double-buffered, one barrier
// per K-iter (compiler's vmcnt(0)@barrier drains the async prefetch).
// BNT=128: waves 2x2 (64x64 each). BNT=64: waves 4x1 (32x64 each).
// bm = blockIdx.x (fastest): XCD = bm%8 stable -> A panels pinned in L2.
// ---------------------------------------------------------------------------
template<int BNT, int BIAS, int RES, int RELU, int OUTBF>
__global__ __launch_bounds__(256) void mgemm(
    const u16* __restrict__ A, const u16* __restrict__ Bt,
    const float* __restrict__ bias, const float* __restrict__ res,
    void* __restrict__ Cv, int M, int N, int K)
{
    constexpr int MI = (BNT == 128) ? 4 : 2;
    __shared__ u16 Al[2][128 * 32];
    __shared__ u16 Bl[2][BNT * 32];
    const int tid = threadIdx.x;
    const int bm = blockIdx.x, bn = blockIdx.y;
    const int wid = tid >> 6, lane = tid & 63;
    const int wr = (BNT == 128) ? (wid >> 1) * 64 : wid * 32;
    const int wc = (BNT == 128) ? (wid & 1) * 64 : 0;
    const int fr = lane & 15, fq = lane >> 4;

    // staging: lane covers row wid*16 + lane/4, 16B chunk (lane&3)*8 elems
    const int l4 = lane >> 2, lc = (lane & 3) * 8;
    const u16* Aga = A  + (size_t)(bm * 128 + wid * 16 + l4) * K + lc;
    const u16* Bga = Bt + (size_t)(bn * BNT + wid * 16 + l4) * K + lc;
    const int lin = (wid * 16 + l4) * 32 + lc;   // linear LDS index (u16)

    f32x4 acc[MI][4];
    #pragma unroll
    for (int i = 0; i < MI; ++i)
        #pragma unroll
        for (int j = 0; j < 4; ++j)
            acc[i][j] = f32x4{0.f, 0.f, 0.f, 0.f};

    // prologue: stage K-tile 0 into buf 0
    gload16(Aga,                  &Al[0][lin]);
    gload16(Aga + (size_t)64 * K, &Al[0][lin + 64 * 32]);
    gload16(Bga,                  &Bl[0][lin]);
    if (BNT == 128) gload16(Bga + (size_t)64 * K, &Bl[0][lin + 64 * 32]);

    int buf = 0;
    for (int k0 = 0; k0 < K; k0 += 32, buf ^= 1) {
        __syncthreads();   // drains vmcnt: buf is loaded; prev reads done
        if (k0 + 32 < K) { // async prefetch next tile; hides under MFMA
            gload16(Aga + k0 + 32,                  &Al[buf ^ 1][lin]);
            gload16(Aga + (size_t)64 * K + k0 + 32, &Al[buf ^ 1][lin + 64 * 32]);
            gload16(Bga + k0 + 32,                  &Bl[buf ^ 1][lin]);
            if (BNT == 128)
                gload16(Bga + (size_t)64 * K + k0 + 32, &Bl[buf ^ 1][lin + 64 * 32]);
        }
        bf16x8v af[MI], bfr[4];
        #pragma unroll
        for (int mi = 0; mi < MI; ++mi)
            af[mi] = *(const bf16x8v*)&Al[buf][(wr + mi * 16 + fr) * 32 + fq * 8];
        #pragma unroll
        for (int ni = 0; ni < 4; ++ni)
            bfr[ni] = *(const bf16x8v*)&Bl[buf][(wc + ni * 16 + fr) * 32 + fq * 8];
        __builtin_amdgcn_s_setprio(1);
        #pragma unroll
        for (int mi = 0; mi < MI; ++mi)
            #pragma unroll
            for (int ni = 0; ni < 4; ++ni)
                acc[mi][ni] = __builtin_amdgcn_mfma_f32_16x16x32_bf16(
                    af[mi], bfr[ni], acc[mi][ni], 0, 0, 0);
        __builtin_amdgcn_s_setprio(0);
    }

    float* Cf = (float*)Cv;
    u16*   Cb = (u16*)Cv;
    #pragma unroll
    for (int mi = 0; mi < MI; ++mi) {
        #pragma unroll
        for (int j = 0; j < 4; ++j) {
            const int r = bm * 128 + wr + mi * 16 + fq * 4 + j;
            #pragma unroll
            for (int ni = 0; ni < 4; ++ni) {
                const int c = bn * BNT + wc + ni * 16 + fr;
                float v = acc[mi][ni][j];
                if (BIAS) v += bias[c];
                if (RELU) v = fmaxf(v, 0.f);
                if (RES)  v += res[(size_t)r * N + c];
                if (OUTBF) Cb[(size_t)r * N + c] = f2bf(v);
                else       Cf[(size_t)r * N + c] = v;
            }
        }
    }
}

// ---------------------------------------------------------------------------
// MFMA causal flash attention (bf16 in/out, fp32 softmax/accum).
// Swapped QK^T: S^T = mfma(K, Q); softmax = 2 shfl_xor; P -> PV B-operand via
// register shuffles. Double-buffered K/V LDS (padded; V needs transposed
// writes so gload_lds doesn't apply) + register prefetch of next tile.
// ---------------------------------------------------------------------------
__global__ __launch_bounds__(256) void attn_kernel(
    const u16* __restrict__ qkv, u16* __restrict__ y)
{
    constexpr int LDK = 72;
    __shared__ u16 Kl[2][64 * LDK];
    __shared__ u16 Vt[2][64 * LDK];

    const int tid = threadIdx.x;
    const int qt = (int)gridDim.x - 1 - (int)blockIdx.x;
    const int bh = blockIdx.y;
    const int b = bh >> 2, h = bh & 3;
    const int w = tid >> 6, lane = tid & 63;
    const int fr = lane & 15, fq = lane >> 4;
    const size_t rowbase = (size_t)b * TBLK;
    const int qoff = h * HSZ, koff = EMB + h * HSZ, voff = 2 * EMB + h * HSZ;
    const int qg = qt * 64 + w * 16 + fr;       // this lane's q row

    bf16x8v qf[2];
    #pragma unroll
    for (int ks = 0; ks < 2; ++ks)
        qf[ks] = *(const bf16x8v*)&qkv[(rowbase + qg) * QKVD + qoff + ks * 32 + fq * 8];

    f32x4 yac[4];
    #pragma unroll
    for (int mi = 0; mi < 4; ++mi) yac[mi] = f32x4{0.f, 0.f, 0.f, 0.f};
    float m = -1e30f, l = 0.f;

    const int skv = tid >> 2, sc = (tid & 3) * 16;
    const u16* kbase = &qkv[(rowbase + skv) * QKVD + koff + sc];
    const u16* vbase = &qkv[(rowbase + skv) * QKVD + voff + sc];

    bf16x8v kr0 = *(const bf16x8v*)kbase;
    bf16x8v kr1 = *(const bf16x8v*)(kbase + 8);
    bf16x8v vr0 = *(const bf16x8v*)vbase;
    bf16x8v vr1 = *(const bf16x8v*)(vbase + 8);

    int buf = 0;
    for (int kv0 = 0; kv0 <= qt * 64; kv0 += 64, buf ^= 1) {
        {   // stage from regs: K row-major, V transposed
            u16* Kw = &Kl[buf][skv * LDK + sc];
            *(bf16x8v*)Kw = kr0; *(bf16x8v*)(Kw + 8) = kr1;
            #pragma unroll
            for (int i = 0; i < 8; ++i) Vt[buf][(sc + i) * LDK + skv] = (u16)vr0[i];
            #pragma unroll
            for (int i = 0; i < 8; ++i) Vt[buf][(sc + 8 + i) * LDK + skv] = (u16)vr1[i];
        }
        __syncthreads();
        if (kv0 + 64 <= qt * 64) {   // prefetch next kv tile
            const size_t off = (size_t)(kv0 + 64) * QKVD;
            kr0 = *(const bf16x8v*)(kbase + off);
            kr1 = *(const bf16x8v*)(kbase + off + 8);
            vr0 = *(const bf16x8v*)(vbase + off);
            vr1 = *(const bf16x8v*)(vbase + off + 8);
        }

        // S^T = K @ Q : frag mb covers kv rows mb*16..+16, lane col = q row fr
        f32x4 st[4];
        __builtin_amdgcn_s_setprio(1);
        #pragma unroll
        for (int mb = 0; mb < 4; ++mb) {
            st[mb] = f32x4{0.f, 0.f, 0.f, 0.f};
            #pragma unroll
            for (int ks = 0; ks < 2; ++ks) {
                const bf16x8v kf = *(const bf16x8v*)
                    &Kl[buf][(mb * 16 + fr) * LDK + ks * 32 + fq * 8];
                st[mb] = __builtin_amdgcn_mfma_f32_16x16x32_bf16(
                    kf, qf[ks], st[mb], 0, 0, 0);
            }
        }
        __builtin_amdgcn_s_setprio(0);
        // mask + online softmax (lane holds kv = kv0+mb*16+fq*4+j for q=qg)
        float p[4][4];
        float mloc = -1e30f;
        #pragma unroll
        for (int mb = 0; mb < 4; ++mb)
            #pragma unroll
            for (int j = 0; j < 4; ++j) {
                const int kvg = kv0 + mb * 16 + fq * 4 + j;
                const float s = (kvg <= qg) ? st[mb][j] * 0.0625f : -1e30f;
                p[mb][j] = s;
                mloc = fmaxf(mloc, s);
            }
        mloc = fmaxf(mloc, __shfl_xor(mloc, 16));
        mloc = fmaxf(mloc, __shfl_xor(mloc, 32));
        const float mnew = fmaxf(m, mloc);
        const float alpha = __expf(m - mnew);
        float rsum = 0.f;
        #pragma unroll
        for (int mb = 0; mb < 4; ++mb)
            #pragma unroll
            for (int j = 0; j < 4; ++j) {
                p[mb][j] = __expf(p[mb][j] - mnew);
                rsum += p[mb][j];
            }
        rsum += __shfl_xor(rsum, 16);
        rsum += __shfl_xor(rsum, 32);
        l = l * alpha + rsum;
        m = mnew;
        #pragma unroll
        for (int mi = 0; mi < 4; ++mi) yac[mi] *= alpha;

        // pack P to bf16 pairs: pk[mb][h2] = {p[2h2], p[2h2+1]}
        u32 pk[4][2];
        #pragma unroll
        for (int mb = 0; mb < 4; ++mb) {
            pk[mb][0] = pack2(p[mb][0], p[mb][1]);
            pk[mb][1] = pack2(p[mb][2], p[mb][3]);
        }
        // y^T += V^T @ P^T ; build P^T B-frags by register shuffle
        #pragma unroll
        for (int ksv = 0; ksv < 2; ++ksv) {
            union { u32 u[4]; bf16x8v v; } pf;
            #pragma unroll
            for (int t = 0; t < 4; ++t) {
                const int srcl = ((fq & 1) * 2 + (t >> 1)) * 16 + fr;
                const u32 lo = __shfl(pk[ksv * 2 + 0][t & 1], srcl);
                const u32 hi = __shfl(pk[ksv * 2 + 1][t & 1], srcl);
                pf.u[t] = (fq >> 1) ? hi : lo;
            }
            __builtin_amdgcn_s_setprio(1);
            #pragma unroll
            for (int mi = 0; mi < 4; ++mi) {
                const bf16x8v vf = *(const bf16x8v*)
                    &Vt[buf][(mi * 16 + fr) * LDK + ksv * 32 + fq * 8];
                yac[mi] = __builtin_amdgcn_mfma_f32_16x16x32_bf16(
                    vf, pf.v, yac[mi], 0, 0, 0);
            }
            __builtin_amdgcn_s_setprio(0);
        }
        // no trailing barrier: next iter writes the other buffer
    }

    // y^T C-layout: row = hs = mi*16+fq*4+j (j consecutive), col = q = fr
    const float inv = 1.f / l;
    #pragma unroll
    for (int mi = 0; mi < 4; ++mi) {
        ushort4 o;
        o.x = f2bf(yac[mi][0] * inv);
        o.y = f2bf(yac[mi][1] * inv);
        o.z = f2bf(yac[mi][2] * inv);
        o.w = f2bf(yac[mi][3] * inv);
        *(ushort4*)&y[(rowbase + qg) * EMB + h * HSZ + mi * 16 + fq * 4] = o;
    }
}

// ---------------------------------------------------------------------------
extern "C" void kernel_launch(void* const* d_in, const int* in_sizes, int n_in,
                              void* d_out, int out_size, void* d_ws, size_t ws_size,
                              hipStream_t stream) {
    const int*   idx   = (const int*)  d_in[0];
    const float* tok   = (const float*)d_in[1];
    const float* pos   = (const float*)d_in[2];
    const float* Wq    = (const float*)d_in[3];
    const float* Wk    = (const float*)d_in[4];
    const float* Wv    = (const float*)d_in[5];
    const float* Wproj = (const float*)d_in[6];
    const float* bproj = (const float*)d_in[7];
    const float* ln1g  = (const float*)d_in[8];
    const float* ln1b  = (const float*)d_in[9];
    const float* W1    = (const float*)d_in[10];
    const float* b1    = (const float*)d_in[11];
    const float* W2    = (const float*)d_in[12];
    const float* b2    = (const float*)d_in[13];
    const float* ln2g  = (const float*)d_in[14];
    const float* ln2b  = (const float*)d_in[15];
    const float* Wlm   = (const float*)d_in[16];
    const float* blm   = (const float*)d_in[17];
    float* out = (float*)d_out;

    // workspace: x(f32) | hb | qkv | yb | transposed bf16 weights
    float* x    = (float*)d_ws;
    u16*   hb   = (u16*)(x + (size_t)BT * EMB);
    u16*   qkvb = hb + (size_t)BT * EMB;
    u16*   yb   = qkvb + (size_t)BT * QKVD;
    u16*   hid  = qkvb;  // [BT][1024] aliases qkv+yb (dead when MLP runs)
    u16*   Wqkvt  = yb + (size_t)BT * EMB;
    u16*   Wprojt = Wqkvt  + (size_t)NLAYER * QKVD * EMB;
    u16*   W1t    = Wprojt + (size_t)NLAYER * EMB * EMB;
    u16*   W2t    = W1t    + (size_t)NLAYER * EMB * 4 * EMB;
    u16*   Wlmt   = W2t    + (size_t)NLAYER * 4 * EMB * EMB;

    const dim3 tb(32, 8);
    transpose_qkvp<<<dim3(8, 8, NLAYER * 4), tb, 0, stream>>>(
        Wq, Wk, Wv, Wproj, Wqkvt, Wprojt);
    transpose_cast<<<dim3(32, 8, NLAYER), tb, 0, stream>>>(
        W1, W1t, EMB, 4*EMB, (size_t)EMB*4*EMB, (size_t)EMB*4*EMB);
    transpose_cast<<<dim3(8, 32, NLAYER), tb, 0, stream>>>(
        W2, W2t, 4*EMB, EMB, (size_t)4*EMB*EMB, (size_t)4*EMB*EMB);
    transpose_cast<<<dim3(VOCAB/32, 8, 1), tb, 0, stream>>>(
        Wlm, Wlmt, EMB, VOCAB, 0, 0);

    embed_kernel<<<BT/4, 256, 0, stream>>>(idx, tok, pos, x);

    for (int l = 0; l < NLAYER; ++l) {
        ln_kernel<<<BT/4, 256, 0, stream>>>(x, ln1g + l*EMB, ln1b + l*EMB, hb);
        mgemm<128,0,0,0,1><<<dim3(BT/128, QKVD/128), 256, 0, stream>>>(
            hb, Wqkvt + (size_t)l*QKVD*EMB, nullptr, nullptr, qkvb, BT, QKVD, EMB);
        attn_kernel<<<dim3(TBLK/64, BATCH*NHEAD), 256, 0, stream>>>(qkvb, yb);
        mgemm<64,1,1,0,0><<<dim3(BT/128, EMB/64), 256, 0, stream>>>(
            yb, Wprojt + (size_t)l*EMB*EMB, bproj + l*EMB, x, x, BT, EMB, EMB);
        ln_kernel<<<BT/4, 256, 0, stream>>>(x, ln2g + l*EMB, ln2b + l*EMB, hb);
        mgemm<128,1,0,1,1><<<dim3(BT/128, 4*EMB/128), 256, 0, stream>>>(
            hb, W1t + (size_t)l*EMB*4*EMB, b1 + l*4*EMB, nullptr, hid, BT, 4*EMB, EMB);
        if (l < NLAYER - 1) {
            mgemm<64,1,1,0,0><<<dim3(BT/128, EMB/64), 256, 0, stream>>>(
                hid, W2t + (size_t)l*4*EMB*EMB, b2 + l*EMB, x, x, BT, EMB, 4*EMB);
        } else {
            // last layer: residual-add then write bf16 directly (x is dead after)
            mgemm<64,1,1,0,1><<<dim3(BT/128, EMB/64), 256, 0, stream>>>(
                hid, W2t + (size_t)l*4*EMB*EMB, b2 + l*EMB, x, hb, BT, EMB, 4*EMB);
        }
    }

    mgemm<128,1,0,0,0><<<dim3(BT/128, VOCAB/128), 256, 0, stream>>>(
        hb, Wlmt, blm, nullptr, out, BT, VOCAB, EMB);
}

// Round 5
// 690.226 us; speedup vs baseline: 9.3543x; 1.0156x over previous
//
#include <hip/hip_runtime.h>
#include <hip/hip_bf16.h>

#define EMB 256
#define NHEAD 4
#define HSZ 64
#define NLAYER 3
#define TBLK 2048
#define VOCAB 32000
#define BATCH 4
#define LNEPS 1e-5f
#define BT (BATCH * TBLK)   // 8192 rows
#define QKVD (3 * EMB)      // 768

typedef __attribute__((ext_vector_type(8))) short bf16x8v;  // 8 bf16 (4 VGPRs)
typedef __attribute__((ext_vector_type(4))) float f32x4;
typedef unsigned short u16;
typedef unsigned int u32;

// round-to-nearest-even f32 -> bf16 bits
__device__ __forceinline__ u16 f2bf(float f) {
    union { float f; u32 u; } c; c.f = f;
    u32 r = c.u + 0x7fff + ((c.u >> 16) & 1);
    return (u16)(r >> 16);
}
__device__ __forceinline__ u32 pack2(float a, float b) {
    return (u32)f2bf(a) | ((u32)f2bf(b) << 16);
}

// async global->LDS, 16 bytes per lane (dest is linear in lane order)
__device__ __forceinline__ void gload16(const u16* g, u16* l) {
    __builtin_amdgcn_global_load_lds(
        (__attribute__((address_space(1))) void*)g,
        (__attribute__((address_space(3))) void*)l, 16, 0, 0);
}

// ---------------------------------------------------------------------------
// Embedding: 4 rows per 256-thr block (one wave per row).
// ---------------------------------------------------------------------------
__global__ __launch_bounds__(256) void embed_kernel(
    const int* __restrict__ idx, const float* __restrict__ tok,
    const float* __restrict__ pos, float* __restrict__ x)
{
    const int row = blockIdx.x * 4 + (threadIdx.x >> 6);
    const int t = row & (TBLK - 1);
    const int token = idx[row];
    const int e = (threadIdx.x & 63) * 4;
    const float4 tv = *(const float4*)&tok[(size_t)token * EMB + e];
    const float4 pv = *(const float4*)&pos[(size_t)t * EMB + e];
    float4 o;
    o.x = tv.x + pv.x; o.y = tv.y + pv.y; o.z = tv.z + pv.z; o.w = tv.w + pv.w;
    *(float4*)&x[(size_t)row * EMB + e] = o;
}

// ---------------------------------------------------------------------------
// LayerNorm (population var) fp32 in -> bf16 out. 4 rows per block.
// ---------------------------------------------------------------------------
__global__ __launch_bounds__(256) void ln_kernel(
    const float* __restrict__ x, const float* __restrict__ g,
    const float* __restrict__ b, u16* __restrict__ out)
{
    const int row = blockIdx.x * 4 + (threadIdx.x >> 6);
    const int e = (threadIdx.x & 63) * 4;
    const float4 xv = *(const float4*)&x[(size_t)row * EMB + e];
    float s1 = xv.x + xv.y + xv.z + xv.w;
    float s2 = xv.x * xv.x + xv.y * xv.y + xv.z * xv.z + xv.w * xv.w;
    #pragma unroll
    for (int off = 32; off >= 1; off >>= 1) {
        s1 += __shfl_xor(s1, off);
        s2 += __shfl_xor(s2, off);
    }
    const float mu  = s1 * (1.0f / EMB);
    const float var = s2 * (1.0f / EMB) - mu * mu;
    const float rs  = rsqrtf(var + LNEPS);
    const float4 gv = *(const float4*)&g[e];
    const float4 bv = *(const float4*)&b[e];
    ushort4 o;
    o.x = f2bf((xv.x - mu) * rs * gv.x + bv.x);
    o.y = f2bf((xv.y - mu) * rs * gv.y + bv.y);
    o.z = f2bf((xv.z - mu) * rs * gv.z + bv.z);
    o.w = f2bf((xv.w - mu) * rs * gv.w + bv.w);
    *(ushort4*)&out[(size_t)row * EMB + e] = o;
}

// ---------------------------------------------------------------------------
// Transpose + cast: W [K][N] f32 -> Wt [N][K] bf16, batched over layers (z).
// ---------------------------------------------------------------------------
__global__ __launch_bounds__(256) void transpose_cast(
    const float* __restrict__ W, u16* __restrict__ Wt, int K, int N,
    size_t sW, size_t sWt)
{
    __shared__ float t[32][33];
    W  += (size_t)blockIdx.z * sW;
    Wt += (size_t)blockIdx.z * sWt;
    const int bx = blockIdx.x, by = blockIdx.y;
    const int tx = threadIdx.x, ty = threadIdx.y;
    #pragma unroll
    for (int i = 0; i < 32; i += 8)
        t[ty + i][tx] = W[(size_t)(by * 32 + ty + i) * N + bx * 32 + tx];
    __syncthreads();
    #pragma unroll
    for (int i = 0; i < 32; i += 8)
        Wt[(size_t)(bx * 32 + ty + i) * K + by * 32 + tx] = f2bf(t[tx][ty + i]);
}

// Fused ExE transposes: z = layer*4 + {Wq,Wk,Wv,Wproj}
__global__ __launch_bounds__(256) void transpose_qkvp(
    const float* __restrict__ Wq, const float* __restrict__ Wk,
    const float* __restrict__ Wv, const float* __restrict__ Wp,
    u16* __restrict__ Wqkvt, u16* __restrict__ Wprojt)
{
    __shared__ float t[32][33];
    const int which = blockIdx.z & 3, l = blockIdx.z >> 2;
    const float* W;
    u16* Wt;
    switch (which) {
        case 0: W = Wq + (size_t)l*EMB*EMB; Wt = Wqkvt + (size_t)l*QKVD*EMB;               break;
        case 1: W = Wk + (size_t)l*EMB*EMB; Wt = Wqkvt + (size_t)l*QKVD*EMB + EMB*EMB;     break;
        case 2: W = Wv + (size_t)l*EMB*EMB; Wt = Wqkvt + (size_t)l*QKVD*EMB + 2*EMB*EMB;   break;
        default:W = Wp + (size_t)l*EMB*EMB; Wt = Wprojt + (size_t)l*EMB*EMB;               break;
    }
    const int bx = blockIdx.x, by = blockIdx.y;
    const int tx = threadIdx.x, ty = threadIdx.y;
    #pragma unroll
    for (int i = 0; i < 32; i += 8)
        t[ty + i][tx] = W[(size_t)(by * 32 + ty + i) * EMB + bx * 32 + tx];
    __syncthreads();
    #pragma unroll
    for (int i = 0; i < 32; i += 8)
        Wt[(size_t)(bx * 32 + ty + i) * EMB + by * 32 + tx] = f2bf(t[tx][ty + i]);
}

// ---------------------------------------------------------------------------
// MFMA GEMM: C[M,N] = A[M,K](bf16) @ Bt[N,K](bf16)^T, fp32 accum.
// 128xBNT tile, BK=32, 256 thr = 4 waves. global_load_lds width-16 staging,
// double-buffered, one barrier/K-iter.
// T2 swizzle (both-sides, rule #21): LDS rows are 64B = 4 chunks of 16B;
// stored chunk c holds global chunk c ^ ((row>>1)&3). Realized by
// pre-swizzling the GLOBAL source column (LDS dest stays linear for
// global_load_lds) and XORing the ds_read chunk. Read banks: 16*(fr&1) +
// 4*(fq^((fr>>1)&3)) -> 8 groups x 2 lanes = 2-way = free (m136).
// BNT=128: waves 2x2 (64x64 each). BNT=64: waves 4x1 (32x64 each).
// bm = blockIdx.x (fastest): XCD = bm%8 stable -> A panels pinned in L2.
// ---------------------------------------------------------------------------
template<int BNT, int BIAS, int RES, int RELU, int OUTBF>
__global__ __launch_bounds__(256) void mgemm(
    const u16* __restrict__ A, const u16* __restrict__ Bt,
    const float* __restrict__ bias, const float* __restrict__ res,
    void* __restrict__ Cv, int M, int N, int K)
{
    constexpr int MI = (BNT == 128) ? 4 : 2;
    __shared__ u16 Al[2][128 * 32];
    __shared__ u16 Bl[2][BNT * 32];
    const int tid = threadIdx.x;
    const int bm = blockIdx.x, bn = blockIdx.y;
    const int wid = tid >> 6, lane = tid & 63;
    const int wr = (BNT == 128) ? (wid >> 1) * 64 : wid * 32;
    const int wc = (BNT == 128) ? (wid & 1) * 64 : 0;
    const int fr = lane & 15, fq = lane >> 4;

    // staging: lane covers row wid*16 + lane/4; source chunk pre-swizzled
    const int l4 = lane >> 2;
    const int lc_src = ((lane & 3) ^ ((l4 >> 1) & 3)) * 8;   // global col (swz)
    const u16* Aga = A  + (size_t)(bm * 128 + wid * 16 + l4) * K + lc_src;
    const u16* Bga = Bt + (size_t)(bn * BNT + wid * 16 + l4) * K + lc_src;
    const int lin = (wid * 16 + l4) * 32 + (lane & 3) * 8;   // linear LDS (u16)

    // read-side swizzled chunk offset (per-lane constant)
    const int rsw = (fq ^ ((fr >> 1) & 3)) * 8;

    f32x4 acc[MI][4];
    #pragma unroll
    for (int i = 0; i < MI; ++i)
        #pragma unroll
        for (int j = 0; j < 4; ++j)
            acc[i][j] = f32x4{0.f, 0.f, 0.f, 0.f};

    // prologue: stage K-tile 0 into buf 0
    gload16(Aga,                  &Al[0][lin]);
    gload16(Aga + (size_t)64 * K, &Al[0][lin + 64 * 32]);
    gload16(Bga,                  &Bl[0][lin]);
    if (BNT == 128) gload16(Bga + (size_t)64 * K, &Bl[0][lin + 64 * 32]);

    int buf = 0;
    for (int k0 = 0; k0 < K; k0 += 32, buf ^= 1) {
        __syncthreads();   // vmcnt(0) drain: buf is loaded; prev reads done
        if (k0 + 32 < K) { // async prefetch next tile; hides under MFMA
            gload16(Aga + k0 + 32,                  &Al[buf ^ 1][lin]);
            gload16(Aga + (size_t)64 * K + k0 + 32, &Al[buf ^ 1][lin + 64 * 32]);
            gload16(Bga + k0 + 32,                  &Bl[buf ^ 1][lin]);
            if (BNT == 128)
                gload16(Bga + (size_t)64 * K + k0 + 32, &Bl[buf ^ 1][lin + 64 * 32]);
        }
        bf16x8v af[MI], bfr[4];
        #pragma unroll
        for (int mi = 0; mi < MI; ++mi)
            af[mi] = *(const bf16x8v*)&Al[buf][(wr + mi * 16 + fr) * 32 + rsw];
        #pragma unroll
        for (int ni = 0; ni < 4; ++ni)
            bfr[ni] = *(const bf16x8v*)&Bl[buf][(wc + ni * 16 + fr) * 32 + rsw];
        #pragma unroll
        for (int mi = 0; mi < MI; ++mi)
            #pragma unroll
            for (int ni = 0; ni < 4; ++ni)
                acc[mi][ni] = __builtin_amdgcn_mfma_f32_16x16x32_bf16(
                    af[mi], bfr[ni], acc[mi][ni], 0, 0, 0);
    }

    float* Cf = (float*)Cv;
    u16*   Cb = (u16*)Cv;
    #pragma unroll
    for (int mi = 0; mi < MI; ++mi) {
        #pragma unroll
        for (int j = 0; j < 4; ++j) {
            const int r = bm * 128 + wr + mi * 16 + fq * 4 + j;
            #pragma unroll
            for (int ni = 0; ni < 4; ++ni) {
                const int c = bn * BNT + wc + ni * 16 + fr;
                float v = acc[mi][ni][j];
                if (BIAS) v += bias[c];
                if (RELU) v = fmaxf(v, 0.f);
                if (RES)  v += res[(size_t)r * N + c];
                if (OUTBF) Cb[(size_t)r * N + c] = f2bf(v);
                else       Cf[(size_t)r * N + c] = v;
            }
        }
    }
}

// ---------------------------------------------------------------------------
// MFMA causal flash attention (bf16 in/out, fp32 softmax/accum).
// Swapped QK^T: S^T = mfma(K, Q); softmax = 2 shfl_xor; P -> PV B-operand via
// register shuffles. Double-buffered K/V LDS (padded LDK=72: stride-36-word
// reads = 2-way = free) + register prefetch of next tile.
// ---------------------------------------------------------------------------
__global__ __launch_bounds__(256) void attn_kernel(
    const u16* __restrict__ qkv, u16* __restrict__ y)
{
    constexpr int LDK = 72;
    __shared__ u16 Kl[2][64 * LDK];
    __shared__ u16 Vt[2][64 * LDK];

    const int tid = threadIdx.x;
    const int qt = (int)gridDim.x - 1 - (int)blockIdx.x;
    const int bh = blockIdx.y;
    const int b = bh >> 2, h = bh & 3;
    const int w = tid >> 6, lane = tid & 63;
    const int fr = lane & 15, fq = lane >> 4;
    const size_t rowbase = (size_t)b * TBLK;
    const int qoff = h * HSZ, koff = EMB + h * HSZ, voff = 2 * EMB + h * HSZ;
    const int qg = qt * 64 + w * 16 + fr;       // this lane's q row

    bf16x8v qf[2];
    #pragma unroll
    for (int ks = 0; ks < 2; ++ks)
        qf[ks] = *(const bf16x8v*)&qkv[(rowbase + qg) * QKVD + qoff + ks * 32 + fq * 8];

    f32x4 yac[4];
    #pragma unroll
    for (int mi = 0; mi < 4; ++mi) yac[mi] = f32x4{0.f, 0.f, 0.f, 0.f};
    float m = -1e30f, l = 0.f;

    const int skv = tid >> 2, sc = (tid & 3) * 16;
    const u16* kbase = &qkv[(rowbase + skv) * QKVD + koff + sc];
    const u16* vbase = &qkv[(rowbase + skv) * QKVD + voff + sc];

    bf16x8v kr0 = *(const bf16x8v*)kbase;
    bf16x8v kr1 = *(const bf16x8v*)(kbase + 8);
    bf16x8v vr0 = *(const bf16x8v*)vbase;
    bf16x8v vr1 = *(const bf16x8v*)(vbase + 8);

    int buf = 0;
    for (int kv0 = 0; kv0 <= qt * 64; kv0 += 64, buf ^= 1) {
        {   // stage from regs: K row-major, V transposed
            u16* Kw = &Kl[buf][skv * LDK + sc];
            *(bf16x8v*)Kw = kr0; *(bf16x8v*)(Kw + 8) = kr1;
            #pragma unroll
            for (int i = 0; i < 8; ++i) Vt[buf][(sc + i) * LDK + skv] = (u16)vr0[i];
            #pragma unroll
            for (int i = 0; i < 8; ++i) Vt[buf][(sc + 8 + i) * LDK + skv] = (u16)vr1[i];
        }
        __syncthreads();
        if (kv0 + 64 <= qt * 64) {   // prefetch next kv tile
            const size_t off = (size_t)(kv0 + 64) * QKVD;
            kr0 = *(const bf16x8v*)(kbase + off);
            kr1 = *(const bf16x8v*)(kbase + off + 8);
            vr0 = *(const bf16x8v*)(vbase + off);
            vr1 = *(const bf16x8v*)(vbase + off + 8);
        }

        // S^T = K @ Q : frag mb covers kv rows mb*16..+16, lane col = q row fr
        f32x4 st[4];
        __builtin_amdgcn_s_setprio(1);
        #pragma unroll
        for (int mb = 0; mb < 4; ++mb) {
            st[mb] = f32x4{0.f, 0.f, 0.f, 0.f};
            #pragma unroll
            for (int ks = 0; ks < 2; ++ks) {
                const bf16x8v kf = *(const bf16x8v*)
                    &Kl[buf][(mb * 16 + fr) * LDK + ks * 32 + fq * 8];
                st[mb] = __builtin_amdgcn_mfma_f32_16x16x32_bf16(
                    kf, qf[ks], st[mb], 0, 0, 0);
            }
        }
        __builtin_amdgcn_s_setprio(0);
        // mask + online softmax (lane holds kv = kv0+mb*16+fq*4+j for q=qg)
        float p[4][4];
        float mloc = -1e30f;
        #pragma unroll
        for (int mb = 0; mb < 4; ++mb)
            #pragma unroll
            for (int j = 0; j < 4; ++j) {
                const int kvg = kv0 + mb * 16 + fq * 4 + j;
                const float s = (kvg <= qg) ? st[mb][j] * 0.0625f : -1e30f;
                p[mb][j] = s;
                mloc = fmaxf(mloc, s);
            }
    mloc = fmaxf(mloc, __shfl_xor(mloc, 16));
        mloc = fmaxf(mloc, __shfl_xor(mloc, 32));
        const float mnew = fmaxf(m, mloc);
        const float alpha = __expf(m - mnew);
        float rsum = 0.f;
        #pragma unroll
        for (int mb = 0; mb < 4; ++mb)
            #pragma unroll
            for (int j = 0; j < 4; ++j) {
                p[mb][j] = __expf(p[mb][j] - mnew);
                rsum += p[mb][j];
            }
        rsum += __shfl_xor(rsum, 16);
        rsum += __shfl_xor(rsum, 32);
        l = l * alpha + rsum;
        m = mnew;
        #pragma unroll
        for (int mi = 0; mi < 4; ++mi) yac[mi] *= alpha;

        // pack P to bf16 pairs: pk[mb][h2] = {p[2h2], p[2h2+1]}
        u32 pk[4][2];
        #pragma unroll
        for (int mb = 0; mb < 4; ++mb) {
            pk[mb][0] = pack2(p[mb][0], p[mb][1]);
            pk[mb][1] = pack2(p[mb][2], p[mb][3]);
        }
        // y^T += V^T @ P^T ; build P^T B-frags by register shuffle
        #pragma unroll
        for (int ksv = 0; ksv < 2; ++ksv) {
            union { u32 u[4]; bf16x8v v; } pf;
            #pragma unroll
            for (int t = 0; t < 4; ++t) {
                const int srcl = ((fq & 1) * 2 + (t >> 1)) * 16 + fr;
                const u32 lo = __shfl(pk[ksv * 2 + 0][t & 1], srcl);
                const u32 hi = __shfl(pk[ksv * 2 + 1][t & 1], srcl);
                pf.u[t] = (fq >> 1) ? hi : lo;
            }
            __builtin_amdgcn_s_setprio(1);
            #pragma unroll
            for (int mi = 0; mi < 4; ++mi) {
                const bf16x8v vf = *(const bf16x8v*)
                    &Vt[buf][(mi * 16 + fr) * LDK + ksv * 32 + fq * 8];
                yac[mi] = __builtin_amdgcn_mfma_f32_16x16x32_bf16(
                    vf, pf.v, yac[mi], 0, 0, 0);
            }
            __builtin_amdgcn_s_setprio(0);
        }
        // no trailing barrier: next iter writes the other buffer
    }

    // y^T C-layout: row = hs = mi*16+fq*4+j (j consecutive), col = q = fr
    const float inv = 1.f / l;
    #pragma unroll
    for (int mi = 0; mi < 4; ++mi) {
        ushort4 o;
        o.x = f2bf(yac[mi][0] * inv);
        o.y = f2bf(yac[mi][1] * inv);
        o.z = f2bf(yac[mi][2] * inv);
        o.w = f2bf(yac[mi][3] * inv);
        *(ushort4*)&y[(rowbase + qg) * EMB + h * HSZ + mi * 16 + fq * 4] = o;
    }
}

// ---------------------------------------------------------------------------
extern "C" void kernel_launch(void* const* d_in, const int* in_sizes, int n_in,
                              void* d_out, int out_size, void* d_ws, size_t ws_size,
                              hipStream_t stream) {
    const int*   idx   = (const int*)  d_in[0];
    const float* tok   = (const float*)d_in[1];
    const float* pos   = (const float*)d_in[2];
    const float* Wq    = (const float*)d_in[3];
    const float* Wk    = (const float*)d_in[4];
    const float* Wv    = (const float*)d_in[5];
    const float* Wproj = (const float*)d_in[6];
    const float* bproj = (const float*)d_in[7];
    const float* ln1g  = (const float*)d_in[8];
    const float* ln1b  = (const float*)d_in[9];
    const float* W1    = (const float*)d_in[10];
    const float* b1    = (const float*)d_in[11];
    const float* W2    = (const float*)d_in[12];
    const float* b2    = (const float*)d_in[13];
    const float* ln2g  = (const float*)d_in[14];
    const float* ln2b  = (const float*)d_in[15];
    const float* Wlm   = (const float*)d_in[16];
    const float* blm   = (const float*)d_in[17];
    float* out = (float*)d_out;

    // workspace: x(f32) | hb | qkv | yb | transposed bf16 weights
    float* x    = (float*)d_ws;
    u16*   hb   = (u16*)(x + (size_t)BT * EMB);
    u16*   qkvb = hb + (size_t)BT * EMB;
    u16*   yb   = qkvb + (size_t)BT * QKVD;
    u16*   hid  = qkvb;  // [BT][1024] aliases qkv+yb (dead when MLP runs)
    u16*   Wqkvt  = yb + (size_t)BT * EMB;
    u16*   Wprojt = Wqkvt  + (size_t)NLAYER * QKVD * EMB;
    u16*   W1t    = Wprojt + (size_t)NLAYER * EMB * EMB;
    u16*   W2t    = W1t    + (size_t)NLAYER * EMB * 4 * EMB;
    u16*   Wlmt   = W2t    + (size_t)NLAYER * 4 * EMB * EMB;

    const dim3 tb(32, 8);
    transpose_qkvp<<<dim3(8, 8, NLAYER * 4), tb, 0, stream>>>(
        Wq, Wk, Wv, Wproj, Wqkvt, Wprojt);
    transpose_cast<<<dim3(32, 8, NLAYER), tb, 0, stream>>>(
        W1, W1t, EMB, 4*EMB, (size_t)EMB*4*EMB, (size_t)EMB*4*EMB);
    transpose_cast<<<dim3(8, 32, NLAYER), tb, 0, stream>>>(
        W2, W2t, 4*EMB, EMB, (size_t)4*EMB*EMB, (size_t)4*EMB*EMB);
    transpose_cast<<<dim3(VOCAB/32, 8, 1), tb, 0, stream>>>(
        Wlm, Wlmt, EMB, VOCAB, 0, 0);

    embed_kernel<<<BT/4, 256, 0, stream>>>(idx, tok, pos, x);

    for (int l = 0; l < NLAYER; ++l) {
        ln_kernel<<<BT/4, 256, 0, stream>>>(x, ln1g + l*EMB, ln1b + l*EMB, hb);
        mgemm<128,0,0,0,1><<<dim3(BT/128, QKVD/128), 256, 0, stream>>>(
            hb, Wqkvt + (size_t)l*QKVD*EMB, nullptr, nullptr, qkvb, BT, QKVD, EMB);
        attn_kernel<<<dim3(TBLK/64, BATCH*NHEAD), 256, 0, stream>>>(qkvb, yb);
        mgemm<64,1,1,0,0><<<dim3(BT/128, EMB/64), 256, 0, stream>>>(
            yb, Wprojt + (size_t)l*EMB*EMB, bproj + l*EMB, x, x, BT, EMB, EMB);
        ln_kernel<<<BT/4, 256, 0, stream>>>(x, ln2g + l*EMB, ln2b + l*EMB, hb);
        mgemm<128,1,0,1,1><<<dim3(BT/128, 4*EMB/128), 256, 0, stream>>>(
            hb, W1t + (size_t)l*EMB*4*EMB, b1 + l*4*EMB, nullptr, hid, BT, 4*EMB, EMB);
        if (l < NLAYER - 1) {
            mgemm<64,1,1,0,0><<<dim3(BT/128, EMB/64), 256, 0, stream>>>(
                hid, W2t + (size_t)l*4*EMB*EMB, b2 + l*EMB, x, x, BT, EMB, 4*EMB);
        } else {
            // last layer: residual-add then write bf16 directly (x is dead after)
            mgemm<64,1,1,0,1><<<dim3(BT/128, EMB/64), 256, 0, stream>>>(
                hid, W2t + (size_t)l*4*EMB*EMB, b2 + l*EMB, x, hb, BT, EMB, 4*EMB);
        }
    }

    mgemm<128,1,0,0,0><<<dim3(BT/128, VOCAB/128), 256, 0, stream>>>(
        hb, Wlmt, blm, nullptr, out, BT, VOCAB, EMB);
}